// Round 1
// baseline (808.286 us; speedup 1.0000x reference)
//
#include <hip/hip_runtime.h>
#include <cstdint>
#include <cstddef>

// ---------- types / helpers ----------
typedef float  f32x4  __attribute__((ext_vector_type(4)));
typedef __bf16 bf16x8 __attribute__((ext_vector_type(8)));
typedef unsigned short u16x8 __attribute__((ext_vector_type(8)));
typedef unsigned short u16x4 __attribute__((ext_vector_type(4)));

__device__ __forceinline__ unsigned short f2bf(float f) {
  union { float f; unsigned int u; } v; v.f = f;
  unsigned int r = v.u + 0x7fffu + ((v.u >> 16) & 1u);   // RNE
  return (unsigned short)(r >> 16);
}
__device__ __forceinline__ float bf2f(unsigned short h) {
  union { unsigned int u; float f; } v; v.u = ((unsigned int)h) << 16;
  return v.f;
}

#define NN 50000
#define EE 800000
#define MPAD 50048   // 391 * 128

// ---------- graph prep ----------
__global__ void gcn_zero_k(int* __restrict__ p, int n) {
  int i = blockIdx.x * 256 + threadIdx.x;
  if (i < n) p[i] = 0;
}

__global__ void gcn_count_k(const int* __restrict__ dst, int* __restrict__ cnt, int E) {
  int e = blockIdx.x * 256 + threadIdx.x;
  if (e < E) atomicAdd(&cnt[dst[e]], 1);
}

// single block, 1024 threads: exclusive scan of cnt -> row_start/cursor, dinv = rsqrt(1+deg)
__global__ void gcn_scan_k(const int* __restrict__ cnt, int* __restrict__ rs,
                           int* __restrict__ cur, float* __restrict__ dinv,
                           int nNodes, int E) {
  __shared__ int sb[1024];
  int t = threadIdx.x;
  const int RUN = (nNodes + 1023) / 1024;
  int begin = t * RUN;
  int end   = begin + RUN; if (end > nNodes) end = nNodes;
  int s = 0;
  for (int i = begin; i < end; i++) s += cnt[i];
  sb[t] = s;
  __syncthreads();
  for (int off = 1; off < 1024; off <<= 1) {
    int x = (t >= off) ? sb[t - off] : 0;
    __syncthreads();
    sb[t] += x;
    __syncthreads();
  }
  int excl = sb[t] - s;
  for (int i = begin; i < end; i++) {
    int v = cnt[i];
    rs[i] = excl; cur[i] = excl;
    dinv[i] = rsqrtf(1.0f + (float)v);
    excl += v;
  }
  if (t == 0) rs[nNodes] = E;
}

__global__ void gcn_scatter_k(const int* __restrict__ src, const int* __restrict__ dst,
                              int* __restrict__ cur, int* __restrict__ es, int E) {
  int e = blockIdx.x * 256 + threadIdx.x;
  if (e < E) {
    int d = dst[e];
    int p = atomicAdd(&cur[d], 1);
    es[p] = src[e];
  }
}

// ---------- dtype conversion ----------
// x [validRows x cols] f32 -> xb [rowsPad x cols] bf16 (pad rows zeroed)
__global__ void gcn_cvt_x_k(const float* __restrict__ x, unsigned short* __restrict__ xb,
                            int rowsPad, int cols, int validRows) {
  int idx = blockIdx.x * 256 + threadIdx.x;
  int total = rowsPad * (cols / 4);
  if (idx >= total) return;
  int e0 = idx * 4;
  int row = e0 / cols;
  u16x4 o;
  if (row < validRows) {
    float4 v = *(const float4*)(x + e0);
    o[0] = f2bf(v.x); o[1] = f2bf(v.y); o[2] = f2bf(v.z); o[3] = f2bf(v.w);
  } else {
    o[0] = 0; o[1] = 0; o[2] = 0; o[3] = 0;
  }
  *(u16x4*)(xb + e0) = o;
}

// W [K x N] f32 -> WT [N x K] bf16
__global__ void gcn_cvt_wT_k(const float* __restrict__ W, unsigned short* __restrict__ WT,
                             int K, int N) {
  int idx = blockIdx.x * 256 + threadIdx.x;
  if (idx >= N * K) return;
  int n = idx / K, k = idx % K;
  WT[idx] = f2bf(W[(size_t)k * N + n]);
}

// ---------- bf16 MFMA GEMM: C[M x N] = A[M x K] * Bt[N x K]^T ----------
// block = 256 threads (4 waves, 2x2 wave grid), block tile 128 x BN,
// wave tile 64 x (BN/2) = 4 x WTN mfma tiles of 16x16, BK = 32.
template<int BN, int WTN>
__global__ __launch_bounds__(256) void gcn_gemm_k(
    const unsigned short* __restrict__ A,   // [Mpad x K] bf16
    const unsigned short* __restrict__ Bt,  // [N x K]    bf16
    unsigned short* __restrict__ C,         // [Mpad x N] bf16
    int K, int N) {
  __shared__ unsigned short lds_a[128 * 32];
  __shared__ unsigned short lds_b[BN * 32];
  const int t = threadIdx.x;
  const int wave = t >> 6, lane = t & 63;
  const int wr = wave >> 1, wc = wave & 1;
  const int quad = lane >> 4, lrow = lane & 15;
  const int m0 = blockIdx.x * 128;
  const int n0 = blockIdx.y * BN;

  f32x4 acc[4][WTN] = {};

  for (int k0 = 0; k0 < K; k0 += 32) {
    __syncthreads();
    // stage A tile 128x32
    for (int q = t; q < 512; q += 256) {
      int r = q >> 2, c = (q & 3) * 8;
      *(u16x8*)&lds_a[r * 32 + c] = *(const u16x8*)&A[(size_t)(m0 + r) * K + k0 + c];
    }
    // stage B tile BNx32 (from Bt rows: already [N][K])
    for (int q = t; q < BN * 4; q += 256) {
      int r = q >> 2, c = (q & 3) * 8;
      *(u16x8*)&lds_b[r * 32 + c] = *(const u16x8*)&Bt[(size_t)(n0 + r) * K + k0 + c];
    }
    __syncthreads();
    bf16x8 af[4], bfr[WTN];
#pragma unroll
    for (int mt = 0; mt < 4; mt++)
      af[mt] = *(const bf16x8*)&lds_a[(wr * 64 + mt * 16 + lrow) * 32 + quad * 8];
#pragma unroll
    for (int nt = 0; nt < WTN; nt++)
      bfr[nt] = *(const bf16x8*)&lds_b[(wc * (BN / 2) + nt * 16 + lrow) * 32 + quad * 8];
#pragma unroll
    for (int mt = 0; mt < 4; mt++)
#pragma unroll
      for (int nt = 0; nt < WTN; nt++)
        acc[mt][nt] = __builtin_amdgcn_mfma_f32_16x16x32_bf16(af[mt], bfr[nt], acc[mt][nt], 0, 0, 0);
  }

  // store C as bf16. D layout: col = lane&15, row = quad*4 + r (verified mapping)
#pragma unroll
  for (int mt = 0; mt < 4; mt++)
#pragma unroll
    for (int nt = 0; nt < WTN; nt++)
#pragma unroll
      for (int r = 0; r < 4; r++) {
        int row = m0 + wr * 64 + mt * 16 + quad * 4 + r;
        int col = n0 + wc * (BN / 2) + nt * 16 + lrow;
        C[(size_t)row * N + col] = f2bf(acc[mt][nt][r]);
      }
}

// ---------- aggregation (gather over sorted edges), fused bias+self+ReLU, bf16 out ----------
template<int D>  // D = 256; 4 features per lane
__global__ __launch_bounds__(256) void gcn_agg_relu_k(
    const unsigned short* __restrict__ h, const int* __restrict__ rs,
    const int* __restrict__ es, const float* __restrict__ dinv,
    const float* __restrict__ bias, unsigned short* __restrict__ out, int nNodes) {
  int wave = threadIdx.x >> 6, lane = threadIdx.x & 63;
  int i = blockIdx.x * 4 + wave;
  if (i >= nNodes) return;
  int f0 = lane * 4;
  float di = dinv[i];
  float acc[4];
  u16x4 hv = *(const u16x4*)&h[(size_t)i * D + f0];
  float w = di * di;
#pragma unroll
  for (int j = 0; j < 4; j++) acc[j] = bf2f(hv[j]) * w;
  int e0 = rs[i], e1 = rs[i + 1];
  for (int e = e0; e < e1; e++) {
    int s = es[e];
    float nrm = dinv[s] * di;
    u16x4 v = *(const u16x4*)&h[(size_t)s * D + f0];
#pragma unroll
    for (int j = 0; j < 4; j++) acc[j] += bf2f(v[j]) * nrm;
  }
#pragma unroll
  for (int j = 0; j < 4; j++) {
    float r = acc[j] + bias[f0 + j];
    out[(size_t)i * D + f0 + j] = f2bf(r > 0.0f ? r : 0.0f);
  }
}

// final layer: D=64, one lane per feature; fused bias + softmax + log_softmax, f32 out
__global__ __launch_bounds__(256) void gcn_agg_final_k(
    const unsigned short* __restrict__ h, const int* __restrict__ rs,
    const int* __restrict__ es, const float* __restrict__ dinv,
    const float* __restrict__ bias, float* __restrict__ out, int nNodes) {
  int wave = threadIdx.x >> 6, lane = threadIdx.x & 63;
  int i = blockIdx.x * 4 + wave;
  if (i >= nNodes) return;
  float di = dinv[i];
  float acc = bf2f(h[(size_t)i * 64 + lane]) * di * di;
  int e0 = rs[i], e1 = rs[i + 1];
  for (int e = e0; e < e1; e++) {
    int s = es[e];
    acc += bf2f(h[(size_t)s * 64 + lane]) * (dinv[s] * di);
  }
  acc += bias[lane];
  // softmax
  float m = acc;
#pragma unroll
  for (int off = 32; off > 0; off >>= 1) m = fmaxf(m, __shfl_xor(m, off));
  float ex = __expf(acc - m);
  float sum = ex;
#pragma unroll
  for (int off = 32; off > 0; off >>= 1) sum += __shfl_xor(sum, off);
  float p = ex / sum;
  // log_softmax(p) = p - log(sum_j exp(p_j)); p in [0,1] so no max needed
  float e2 = __expf(p);
  float s2 = e2;
#pragma unroll
  for (int off = 32; off > 0; off >>= 1) s2 += __shfl_xor(s2, off);
  out[(size_t)i * 64 + lane] = p - __logf(s2);
}

// ---------- launch ----------
extern "C" void kernel_launch(void* const* d_in, const int* in_sizes, int n_in,
                              void* d_out, int out_size, void* d_ws, size_t ws_size,
                              hipStream_t stream) {
  const float* x    = (const float*)d_in[0];
  const int*   eidx = (const int*)d_in[1];
  const float* W1   = (const float*)d_in[2];
  const float* b1   = (const float*)d_in[3];
  const float* W2   = (const float*)d_in[4];
  const float* b2   = (const float*)d_in[5];
  const float* W3   = (const float*)d_in[6];
  const float* b3   = (const float*)d_in[7];
  float* out = (float*)d_out;

  const int E = in_sizes[1] / 2;            // 800000
  const int* src = eidx;
  const int* dst = eidx + E;

  // workspace carve-up (256B aligned)
  char* p = (char*)d_ws;
  auto alloc = [&](size_t bytes) -> void* {
    void* r = (void*)p;
    p += (bytes + 255) & ~(size_t)255;
    return r;
  };
  unsigned short* xb  = (unsigned short*)alloc((size_t)MPAD * 512 * 2);
  unsigned short* hb  = (unsigned short*)alloc((size_t)MPAD * 256 * 2);  // gemm out (h)
  unsigned short* ab  = (unsigned short*)alloc((size_t)MPAD * 256 * 2);  // agg+relu out
  unsigned short* h3  = (unsigned short*)alloc((size_t)MPAD * 64 * 2);
  unsigned short* W1T = (unsigned short*)alloc((size_t)256 * 512 * 2);
  unsigned short* W2T = (unsigned short*)alloc((size_t)256 * 256 * 2);
  unsigned short* W3T = (unsigned short*)alloc((size_t)64 * 256 * 2);
  int*   cnt  = (int*)alloc((size_t)NN * 4);
  int*   rs   = (int*)alloc((size_t)(NN + 1) * 4);
  int*   cur  = (int*)alloc((size_t)NN * 4);
  float* dinv = (float*)alloc((size_t)NN * 4);
  int*   es   = (int*)alloc((size_t)E * 4);

  // graph prep (degree count -> scan -> sort edges by dst)
  gcn_zero_k<<<(NN + 255) / 256, 256, 0, stream>>>(cnt, NN);
  gcn_count_k<<<(E + 255) / 256, 256, 0, stream>>>(dst, cnt, E);
  gcn_scan_k<<<1, 1024, 0, stream>>>(cnt, rs, cur, dinv, NN, E);
  gcn_scatter_k<<<(E + 255) / 256, 256, 0, stream>>>(src, dst, cur, es, E);

  // dtype conversions
  gcn_cvt_x_k<<<((MPAD * 512 / 4) + 255) / 256, 256, 0, stream>>>(x, xb, MPAD, 512, NN);
  gcn_cvt_wT_k<<<(256 * 512 + 255) / 256, 256, 0, stream>>>(W1, W1T, 512, 256);
  gcn_cvt_wT_k<<<(256 * 256 + 255) / 256, 256, 0, stream>>>(W2, W2T, 256, 256);
  gcn_cvt_wT_k<<<(64 * 256 + 255) / 256, 256, 0, stream>>>(W3, W3T, 256, 64);

  const int MB = MPAD / 128;  // 391
  // layer 1
  gcn_gemm_k<128, 4><<<dim3(MB, 2), 256, 0, stream>>>(xb, W1T, hb, 512, 256);
  gcn_agg_relu_k<256><<<(NN + 3) / 4, 256, 0, stream>>>(hb, rs, es, dinv, b1, ab, NN);
  // layer 2
  gcn_gemm_k<128, 4><<<dim3(MB, 2), 256, 0, stream>>>(ab, W2T, hb, 256, 256);
  gcn_agg_relu_k<256><<<(NN + 3) / 4, 256, 0, stream>>>(hb, rs, es, dinv, b2, ab, NN);
  // layer 3 + fused softmax/log_softmax
  gcn_gemm_k<64, 2><<<dim3(MB, 1), 256, 0, stream>>>(ab, W3T, h3, 256, 64);
  gcn_agg_final_k<<<(NN + 3) / 4, 256, 0, stream>>>(h3, rs, es, dinv, b3, out, NN);

  (void)n_in; (void)out_size; (void)ws_size;
}

// Round 2
// 678.251 us; speedup vs baseline: 1.1917x; 1.1917x over previous
//
#include <hip/hip_runtime.h>
#include <cstdint>
#include <cstddef>

// ---------- types / helpers ----------
typedef float  f32x4  __attribute__((ext_vector_type(4)));
typedef __bf16 bf16x8 __attribute__((ext_vector_type(8)));
typedef unsigned short u16x8 __attribute__((ext_vector_type(8)));
typedef unsigned short u16x4 __attribute__((ext_vector_type(4)));

__device__ __forceinline__ unsigned short f2bf(float f) {
  union { float f; unsigned int u; } v; v.f = f;
  unsigned int r = v.u + 0x7fffu + ((v.u >> 16) & 1u);   // RNE
  return (unsigned short)(r >> 16);
}
__device__ __forceinline__ float bf2f(unsigned short h) {
  union { unsigned int u; float f; } v; v.u = ((unsigned int)h) << 16;
  return v.f;
}

#define NN 50000
#define EE 800000
#define MPAD 50048   // 391 * 128
#define SCAN_BLOCKS 196  // ceil(50000/256)

// ---------- graph prep ----------
__global__ void gcn_zero_k(int* __restrict__ p, int n) {
  int i = blockIdx.x * 256 + threadIdx.x;
  if (i < n) p[i] = 0;
}

__global__ void gcn_count_k(const int* __restrict__ dst, int* __restrict__ cnt, int E) {
  int e = blockIdx.x * 256 + threadIdx.x;
  if (e < E) atomicAdd(&cnt[dst[e]], 1);
}

// ---- 3-dispatch parallel exclusive scan of cnt[0..NN) ----
__global__ __launch_bounds__(256) void gcn_scan_blocks_k(
    const int* __restrict__ cnt, int* __restrict__ blockSum, int nNodes) {
  __shared__ int sw[4];
  int t = threadIdx.x;
  int i = blockIdx.x * 256 + t;
  int v = (i < nNodes) ? cnt[i] : 0;
  for (int off = 32; off > 0; off >>= 1) v += __shfl_down(v, off);
  if ((t & 63) == 0) sw[t >> 6] = v;
  __syncthreads();
  if (t == 0) blockSum[blockIdx.x] = sw[0] + sw[1] + sw[2] + sw[3];
}

__global__ __launch_bounds__(256) void gcn_scan_tops_k(
    int* __restrict__ blockSum, int nBlocks) {
  __shared__ int sb[256];
  int t = threadIdx.x;
  int v = (t < nBlocks) ? blockSum[t] : 0;
  sb[t] = v;
  __syncthreads();
  for (int off = 1; off < 256; off <<= 1) {
    int x = (t >= off) ? sb[t - off] : 0;
    __syncthreads();
    sb[t] += x;
    __syncthreads();
  }
  if (t < nBlocks) blockSum[t] = sb[t] - v;  // exclusive
}

__global__ __launch_bounds__(256) void gcn_scan_final_k(
    const int* __restrict__ cnt, const int* __restrict__ blockSum,
    int* __restrict__ rs, int* __restrict__ cur, float* __restrict__ dinv,
    int nNodes, int E) {
  __shared__ int sb[256];
  int t = threadIdx.x;
  int i = blockIdx.x * 256 + t;
  int v = (i < nNodes) ? cnt[i] : 0;
  sb[t] = v;
  __syncthreads();
  for (int off = 1; off < 256; off <<= 1) {
    int x = (t >= off) ? sb[t - off] : 0;
    __syncthreads();
    sb[t] += x;
    __syncthreads();
  }
  if (i < nNodes) {
    int off = blockSum[blockIdx.x] + sb[t] - v;  // exclusive prefix
    rs[i] = off; cur[i] = off;
    dinv[i] = rsqrtf(1.0f + (float)v);
  }
  if (i == 0) rs[nNodes] = E;
}

__global__ void gcn_scatter_k(const int* __restrict__ src, const int* __restrict__ dst,
                              int* __restrict__ cur, int* __restrict__ es, int E) {
  int e = blockIdx.x * 256 + threadIdx.x;
  if (e < E) {
    int d = dst[e];
    int p = atomicAdd(&cur[d], 1);
    es[p] = src[e];
  }
}

// ---------- dtype conversion ----------
__global__ void gcn_cvt_x_k(const float* __restrict__ x, unsigned short* __restrict__ xb,
                            int rowsPad, int cols, int validRows) {
  int idx = blockIdx.x * 256 + threadIdx.x;
  int total = rowsPad * (cols / 4);
  if (idx >= total) return;
  int e0 = idx * 4;
  int row = e0 / cols;
  u16x4 o;
  if (row < validRows) {
    float4 v = *(const float4*)(x + e0);
    o[0] = f2bf(v.x); o[1] = f2bf(v.y); o[2] = f2bf(v.z); o[3] = f2bf(v.w);
  } else {
    o[0] = 0; o[1] = 0; o[2] = 0; o[3] = 0;
  }
  *(u16x4*)(xb + e0) = o;
}

__global__ void gcn_cvt_wT_k(const float* __restrict__ W, unsigned short* __restrict__ WT,
                             int K, int N) {
  int idx = blockIdx.x * 256 + threadIdx.x;
  if (idx >= N * K) return;
  int n = idx / K, k = idx % K;
  WT[idx] = f2bf(W[(size_t)k * N + n]);
}

// ---------- bf16 MFMA GEMM: C[M x N] = A[M x K] * Bt[N x K]^T ----------
template<int BN, int WTN>
__global__ __launch_bounds__(256) void gcn_gemm_k(
    const unsigned short* __restrict__ A,   // [Mpad x K] bf16
    const unsigned short* __restrict__ Bt,  // [N x K]    bf16
    unsigned short* __restrict__ C,         // [Mpad x N] bf16
    int K, int N) {
  __shared__ unsigned short lds_a[128 * 32];
  __shared__ unsigned short lds_b[BN * 32];
  const int t = threadIdx.x;
  const int wave = t >> 6, lane = t & 63;
  const int wr = wave >> 1, wc = wave & 1;
  const int quad = lane >> 4, lrow = lane & 15;
  const int m0 = blockIdx.x * 128;
  const int n0 = blockIdx.y * BN;

  f32x4 acc[4][WTN] = {};

  for (int k0 = 0; k0 < K; k0 += 32) {
    __syncthreads();
    for (int q = t; q < 512; q += 256) {
      int r = q >> 2, c = (q & 3) * 8;
      *(u16x8*)&lds_a[r * 32 + c] = *(const u16x8*)&A[(size_t)(m0 + r) * K + k0 + c];
    }
    for (int q = t; q < BN * 4; q += 256) {
      int r = q >> 2, c = (q & 3) * 8;
      *(u16x8*)&lds_b[r * 32 + c] = *(const u16x8*)&Bt[(size_t)(n0 + r) * K + k0 + c];
    }
    __syncthreads();
    bf16x8 af[4], bfr[WTN];
#pragma unroll
    for (int mt = 0; mt < 4; mt++)
      af[mt] = *(const bf16x8*)&lds_a[(wr * 64 + mt * 16 + lrow) * 32 + quad * 8];
#pragma unroll
    for (int nt = 0; nt < WTN; nt++)
      bfr[nt] = *(const bf16x8*)&lds_b[(wc * (BN / 2) + nt * 16 + lrow) * 32 + quad * 8];
#pragma unroll
    for (int mt = 0; mt < 4; mt++)
#pragma unroll
      for (int nt = 0; nt < WTN; nt++)
        acc[mt][nt] = __builtin_amdgcn_mfma_f32_16x16x32_bf16(af[mt], bfr[nt], acc[mt][nt], 0, 0, 0);
  }

#pragma unroll
  for (int mt = 0; mt < 4; mt++)
#pragma unroll
    for (int nt = 0; nt < WTN; nt++)
#pragma unroll
      for (int r = 0; r < 4; r++) {
        int row = m0 + wr * 64 + mt * 16 + quad * 4 + r;
        int col = n0 + wc * (BN / 2) + nt * 16 + lrow;
        C[(size_t)row * N + col] = f2bf(acc[mt][nt][r]);
      }
}

// ---------- aggregation (gather over sorted edges), fused bias+self+ReLU, bf16 out ----------
template<int D>  // D = 256; 4 features per lane
__global__ __launch_bounds__(256) void gcn_agg_relu_k(
    const unsigned short* __restrict__ h, const int* __restrict__ rs,
    const int* __restrict__ es, const float* __restrict__ dinv,
    const float* __restrict__ bias, unsigned short* __restrict__ out, int nNodes) {
  int wave = threadIdx.x >> 6, lane = threadIdx.x & 63;
  int i = blockIdx.x * 4 + wave;
  if (i >= nNodes) return;
  int f0 = lane * 4;
  float di = dinv[i];
  float acc[4];
  u16x4 hv = *(const u16x4*)&h[(size_t)i * D + f0];
  float w = di * di;
#pragma unroll
  for (int j = 0; j < 4; j++) acc[j] = bf2f(hv[j]) * w;
  int e0 = rs[i], e1 = rs[i + 1];
  for (int e = e0; e < e1; e++) {
    int s = es[e];
    float nrm = dinv[s] * di;
    u16x4 v = *(const u16x4*)&h[(size_t)s * D + f0];
#pragma unroll
    for (int j = 0; j < 4; j++) acc[j] += bf2f(v[j]) * nrm;
  }
#pragma unroll
  for (int j = 0; j < 4; j++) {
    float r = acc[j] + bias[f0 + j];
    out[(size_t)i * D + f0 + j] = f2bf(r > 0.0f ? r : 0.0f);
  }
}

// final layer: D=64, one lane per feature; fused bias + softmax + log_softmax, f32 out
__global__ __launch_bounds__(256) void gcn_agg_final_k(
    const unsigned short* __restrict__ h, const int* __restrict__ rs,
    const int* __restrict__ es, const float* __restrict__ dinv,
    const float* __restrict__ bias, float* __restrict__ out, int nNodes) {
  int wave = threadIdx.x >> 6, lane = threadIdx.x & 63;
  int i = blockIdx.x * 4 + wave;
  if (i >= nNodes) return;
  float di = dinv[i];
  float acc = bf2f(h[(size_t)i * 64 + lane]) * di * di;
  int e0 = rs[i], e1 = rs[i + 1];
  for (int e = e0; e < e1; e++) {
    int s = es[e];
    acc += bf2f(h[(size_t)s * 64 + lane]) * (dinv[s] * di);
  }
  acc += bias[lane];
  float m = acc;
#pragma unroll
  for (int off = 32; off > 0; off >>= 1) m = fmaxf(m, __shfl_xor(m, off));
  float ex = __expf(acc - m);
  float sum = ex;
#pragma unroll
  for (int off = 32; off > 0; off >>= 1) sum += __shfl_xor(sum, off);
  float p = ex / sum;
  float e2 = __expf(p);
  float s2 = e2;
#pragma unroll
  for (int off = 32; off > 0; off >>= 1) s2 += __shfl_xor(s2, off);
  out[(size_t)i * 64 + lane] = p - __logf(s2);
}

// ---------- launch ----------
extern "C" void kernel_launch(void* const* d_in, const int* in_sizes, int n_in,
                              void* d_out, int out_size, void* d_ws, size_t ws_size,
                              hipStream_t stream) {
  const float* x    = (const float*)d_in[0];
  const int*   eidx = (const int*)d_in[1];
  const float* W1   = (const float*)d_in[2];
  const float* b1   = (const float*)d_in[3];
  const float* W2   = (const float*)d_in[4];
  const float* b2   = (const float*)d_in[5];
  const float* W3   = (const float*)d_in[6];
  const float* b3   = (const float*)d_in[7];
  float* out = (float*)d_out;

  const int E = in_sizes[1] / 2;            // 800000
  const int* src = eidx;
  const int* dst = eidx + E;

  char* p = (char*)d_ws;
  auto alloc = [&](size_t bytes) -> void* {
    void* r = (void*)p;
    p += (bytes + 255) & ~(size_t)255;
    return r;
  };
  unsigned short* xb  = (unsigned short*)alloc((size_t)MPAD * 512 * 2);
  unsigned short* hb  = (unsigned short*)alloc((size_t)MPAD * 256 * 2);
  unsigned short* ab  = (unsigned short*)alloc((size_t)MPAD * 256 * 2);
  unsigned short* h3  = (unsigned short*)alloc((size_t)MPAD * 64 * 2);
  unsigned short* W1T = (unsigned short*)alloc((size_t)256 * 512 * 2);
  unsigned short* W2T = (unsigned short*)alloc((size_t)256 * 256 * 2);
  unsigned short* W3T = (unsigned short*)alloc((size_t)64 * 256 * 2);
  int*   cnt  = (int*)alloc((size_t)NN * 4);
  int*   rs   = (int*)alloc((size_t)(NN + 1) * 4);
  int*   cur  = (int*)alloc((size_t)NN * 4);
  float* dinv = (float*)alloc((size_t)NN * 4);
  int*   es   = (int*)alloc((size_t)E * 4);
  int*   bsum = (int*)alloc((size_t)SCAN_BLOCKS * 4);

  gcn_zero_k<<<(NN + 255) / 256, 256, 0, stream>>>(cnt, NN);
  gcn_count_k<<<(E + 255) / 256, 256, 0, stream>>>(dst, cnt, E);
  gcn_scan_blocks_k<<<SCAN_BLOCKS, 256, 0, stream>>>(cnt, bsum, NN);
  gcn_scan_tops_k<<<1, 256, 0, stream>>>(bsum, SCAN_BLOCKS);
  gcn_scan_final_k<<<SCAN_BLOCKS, 256, 0, stream>>>(cnt, bsum, rs, cur, dinv, NN, E);
  gcn_scatter_k<<<(E + 255) / 256, 256, 0, stream>>>(src, dst, cur, es, E);

  gcn_cvt_x_k<<<((MPAD * 512 / 4) + 255) / 256, 256, 0, stream>>>(x, xb, MPAD, 512, NN);
  gcn_cvt_wT_k<<<(256 * 512 + 255) / 256, 256, 0, stream>>>(W1, W1T, 512, 256);
  gcn_cvt_wT_k<<<(256 * 256 + 255) / 256, 256, 0, stream>>>(W2, W2T, 256, 256);
  gcn_cvt_wT_k<<<(64 * 256 + 255) / 256, 256, 0, stream>>>(W3, W3T, 256, 64);

  const int MB = MPAD / 128;  // 391
  gcn_gemm_k<128, 4><<<dim3(MB, 2), 256, 0, stream>>>(xb, W1T, hb, 512, 256);
  gcn_agg_relu_k<256><<<(NN + 3) / 4, 256, 0, stream>>>(hb, rs, es, dinv, b1, ab, NN);
  gcn_gemm_k<128, 4><<<dim3(MB, 2), 256, 0, stream>>>(ab, W2T, hb, 256, 256);
  gcn_agg_relu_k<256><<<(NN + 3) / 4, 256, 0, stream>>>(hb, rs, es, dinv, b2, ab, NN);
  gcn_gemm_k<64, 2><<<dim3(MB, 1), 256, 0, stream>>>(ab, W3T, h3, 256, 64);
  gcn_agg_final_k<<<(NN + 3) / 4, 256, 0, stream>>>(h3, rs, es, dinv, b3, out, NN);

  (void)n_in; (void)out_size; (void)ws_size;
}

// Round 3
// 521.602 us; speedup vs baseline: 1.5496x; 1.3003x over previous
//
#include <hip/hip_runtime.h>
#include <cstdint>
#include <cstddef>

// ---------- types / helpers ----------
typedef float  f32x4  __attribute__((ext_vector_type(4)));
typedef __bf16 bf16x8 __attribute__((ext_vector_type(8)));
typedef unsigned short u16x8 __attribute__((ext_vector_type(8)));
typedef unsigned short u16x4 __attribute__((ext_vector_type(4)));

__device__ __forceinline__ unsigned short f2bf(float f) {
  union { float f; unsigned int u; } v; v.f = f;
  unsigned int r = v.u + 0x7fffu + ((v.u >> 16) & 1u);   // RNE
  return (unsigned short)(r >> 16);
}
__device__ __forceinline__ float bf2f(unsigned short h) {
  union { unsigned int u; float f; } v; v.u = ((unsigned int)h) << 16;
  return v.f;
}

#define NN 50000
#define EE 800000
#define MPAD 50048   // 391 * 128
#define SCAN_BLOCKS 196  // ceil(50000/256)

// ---------- graph prep ----------
__global__ void gcn_zero_k(int* __restrict__ p, int n) {
  int i = blockIdx.x * 256 + threadIdx.x;
  if (i < n) p[i] = 0;
}

__global__ void gcn_count_k(const int* __restrict__ dst, int* __restrict__ cnt, int E) {
  int e = blockIdx.x * 256 + threadIdx.x;
  if (e < E) atomicAdd(&cnt[dst[e]], 1);
}

// ---- 3-dispatch parallel exclusive scan of cnt[0..NN) ----
__global__ __launch_bounds__(256) void gcn_scan_blocks_k(
    const int* __restrict__ cnt, int* __restrict__ blockSum, int nNodes) {
  __shared__ int sw[4];
  int t = threadIdx.x;
  int i = blockIdx.x * 256 + t;
  int v = (i < nNodes) ? cnt[i] : 0;
  for (int off = 32; off > 0; off >>= 1) v += __shfl_down(v, off);
  if ((t & 63) == 0) sw[t >> 6] = v;
  __syncthreads();
  if (t == 0) blockSum[blockIdx.x] = sw[0] + sw[1] + sw[2] + sw[3];
}

__global__ __launch_bounds__(256) void gcn_scan_tops_k(
    int* __restrict__ blockSum, int nBlocks) {
  __shared__ int sb[256];
  int t = threadIdx.x;
  int v = (t < nBlocks) ? blockSum[t] : 0;
  sb[t] = v;
  __syncthreads();
  for (int off = 1; off < 256; off <<= 1) {
    int x = (t >= off) ? sb[t - off] : 0;
    __syncthreads();
    sb[t] += x;
    __syncthreads();
  }
  if (t < nBlocks) blockSum[t] = sb[t] - v;  // exclusive
}

__global__ __launch_bounds__(256) void gcn_scan_final_k(
    const int* __restrict__ cnt, const int* __restrict__ blockSum,
    int* __restrict__ rs, int* __restrict__ cur, float* __restrict__ dinv,
    int nNodes, int E) {
  __shared__ int sb[256];
  int t = threadIdx.x;
  int i = blockIdx.x * 256 + t;
  int v = (i < nNodes) ? cnt[i] : 0;
  sb[t] = v;
  __syncthreads();
  for (int off = 1; off < 256; off <<= 1) {
    int x = (t >= off) ? sb[t - off] : 0;
    __syncthreads();
    sb[t] += x;
    __syncthreads();
  }
  if (i < nNodes) {
    int off = blockSum[blockIdx.x] + sb[t] - v;  // exclusive prefix
    rs[i] = off; cur[i] = off;
    dinv[i] = rsqrtf(1.0f + (float)v);
  }
  if (i == 0) rs[nNodes] = E;
}

// scatter edges sorted by dst; also precompute per-edge norm = dinv[src]*dinv[dst]
__global__ void gcn_scatter_k(const int* __restrict__ src, const int* __restrict__ dst,
                              int* __restrict__ cur, const float* __restrict__ dinv,
                              int* __restrict__ es, float* __restrict__ ew, int E) {
  int e = blockIdx.x * 256 + threadIdx.x;
  if (e < E) {
    int d = dst[e];
    int s = src[e];
    int p = atomicAdd(&cur[d], 1);
    es[p] = s;
    ew[p] = dinv[s] * dinv[d];
  }
}

// ---------- dtype conversion ----------
__global__ void gcn_cvt_x_k(const float* __restrict__ x, unsigned short* __restrict__ xb,
                            int rowsPad, int cols, int validRows) {
  int idx = blockIdx.x * 256 + threadIdx.x;
  int total = rowsPad * (cols / 4);
  if (idx >= total) return;
  int e0 = idx * 4;
  int row = e0 / cols;
  u16x4 o;
  if (row < validRows) {
    float4 v = *(const float4*)(x + e0);
    o[0] = f2bf(v.x); o[1] = f2bf(v.y); o[2] = f2bf(v.z); o[3] = f2bf(v.w);
  } else {
    o[0] = 0; o[1] = 0; o[2] = 0; o[3] = 0;
  }
  *(u16x4*)(xb + e0) = o;
}

__global__ void gcn_cvt_wT_k(const float* __restrict__ W, unsigned short* __restrict__ WT,
                             int K, int N) {
  int idx = blockIdx.x * 256 + threadIdx.x;
  if (idx >= N * K) return;
  int n = idx / K, k = idx % K;
  WT[idx] = f2bf(W[(size_t)k * N + n]);
}

// ---------- bf16 MFMA GEMM: C[M x N] = A[M x K] * Bt[N x K]^T ----------
template<int BN, int WTN>
__global__ __launch_bounds__(256) void gcn_gemm_k(
    const unsigned short* __restrict__ A,   // [Mpad x K] bf16
    const unsigned short* __restrict__ Bt,  // [N x K]    bf16
    unsigned short* __restrict__ C,         // [Mpad x N] bf16
    int K, int N) {
  __shared__ unsigned short lds_a[128 * 32];
  __shared__ unsigned short lds_b[BN * 32];
  const int t = threadIdx.x;
  const int wave = t >> 6, lane = t & 63;
  const int wr = wave >> 1, wc = wave & 1;
  const int quad = lane >> 4, lrow = lane & 15;
  const int m0 = blockIdx.x * 128;
  const int n0 = blockIdx.y * BN;

  f32x4 acc[4][WTN] = {};

  for (int k0 = 0; k0 < K; k0 += 32) {
    __syncthreads();
    for (int q = t; q < 512; q += 256) {
      int r = q >> 2, c = (q & 3) * 8;
      *(u16x8*)&lds_a[r * 32 + c] = *(const u16x8*)&A[(size_t)(m0 + r) * K + k0 + c];
    }
    for (int q = t; q < BN * 4; q += 256) {
      int r = q >> 2, c = (q & 3) * 8;
      *(u16x8*)&lds_b[r * 32 + c] = *(const u16x8*)&Bt[(size_t)(n0 + r) * K + k0 + c];
    }
    __syncthreads();
    bf16x8 af[4], bfr[WTN];
#pragma unroll
    for (int mt = 0; mt < 4; mt++)
      af[mt] = *(const bf16x8*)&lds_a[(wr * 64 + mt * 16 + lrow) * 32 + quad * 8];
#pragma unroll
    for (int nt = 0; nt < WTN; nt++)
      bfr[nt] = *(const bf16x8*)&lds_b[(wc * (BN / 2) + nt * 16 + lrow) * 32 + quad * 8];
#pragma unroll
    for (int mt = 0; mt < 4; mt++)
#pragma unroll
      for (int nt = 0; nt < WTN; nt++)
        acc[mt][nt] = __builtin_amdgcn_mfma_f32_16x16x32_bf16(af[mt], bfr[nt], acc[mt][nt], 0, 0, 0);
  }

#pragma unroll
  for (int mt = 0; mt < 4; mt++)
#pragma unroll
    for (int nt = 0; nt < WTN; nt++)
#pragma unroll
      for (int r = 0; r < 4; r++) {
        int row = m0 + wr * 64 + mt * 16 + quad * 4 + r;
        int col = n0 + wc * (BN / 2) + nt * 16 + lrow;
        C[(size_t)row * N + col] = f2bf(acc[mt][nt][r]);
      }
}

// ---------- aggregation (gather over sorted edges), fused bias+self+ReLU, bf16 out ----------
// Unrolled x4 for memory-level parallelism: es/ew are sequential streams,
// only the h-row gather is random; 4 row loads kept in flight per wave.
template<int D>  // D = 256; 4 features per lane
__global__ __launch_bounds__(256) void gcn_agg_relu_k(
    const unsigned short* __restrict__ h, const int* __restrict__ rs,
    const int* __restrict__ es, const float* __restrict__ ew,
    const float* __restrict__ dinv,
    const float* __restrict__ bias, unsigned short* __restrict__ out, int nNodes) {
  int wave = threadIdx.x >> 6, lane = threadIdx.x & 63;
  int i = blockIdx.x * 4 + wave;
  if (i >= nNodes) return;
  int f0 = lane * 4;
  float di = dinv[i];
  float acc[4];
  u16x4 hv = *(const u16x4*)&h[(size_t)i * D + f0];
  float w = di * di;
#pragma unroll
  for (int j = 0; j < 4; j++) acc[j] = bf2f(hv[j]) * w;
  int e0 = rs[i], e1 = rs[i + 1];
  int e = e0;
  for (; e + 4 <= e1; e += 4) {
    int s0 = es[e], s1 = es[e + 1], s2 = es[e + 2], s3 = es[e + 3];
    float w0 = ew[e], w1 = ew[e + 1], w2 = ew[e + 2], w3 = ew[e + 3];
    u16x4 v0 = *(const u16x4*)&h[(size_t)s0 * D + f0];
    u16x4 v1 = *(const u16x4*)&h[(size_t)s1 * D + f0];
    u16x4 v2 = *(const u16x4*)&h[(size_t)s2 * D + f0];
    u16x4 v3 = *(const u16x4*)&h[(size_t)s3 * D + f0];
#pragma unroll
    for (int j = 0; j < 4; j++) {
      acc[j] += bf2f(v0[j]) * w0;
      acc[j] += bf2f(v1[j]) * w1;
      acc[j] += bf2f(v2[j]) * w2;
      acc[j] += bf2f(v3[j]) * w3;
    }
  }
  for (; e < e1; e++) {
    int s = es[e];
    float we = ew[e];
    u16x4 v = *(const u16x4*)&h[(size_t)s * D + f0];
#pragma unroll
    for (int j = 0; j < 4; j++) acc[j] += bf2f(v[j]) * we;
  }
#pragma unroll
  for (int j = 0; j < 4; j++) {
    float r = acc[j] + bias[f0 + j];
    out[(size_t)i * D + f0 + j] = f2bf(r > 0.0f ? r : 0.0f);
  }
}

// final layer: D=64, one lane per feature; fused bias + softmax + log_softmax, f32 out
__global__ __launch_bounds__(256) void gcn_agg_final_k(
    const unsigned short* __restrict__ h, const int* __restrict__ rs,
    const int* __restrict__ es, const float* __restrict__ ew,
    const float* __restrict__ dinv,
    const float* __restrict__ bias, float* __restrict__ out, int nNodes) {
  int wave = threadIdx.x >> 6, lane = threadIdx.x & 63;
  int i = blockIdx.x * 4 + wave;
  if (i >= nNodes) return;
  float di = dinv[i];
  float acc = bf2f(h[(size_t)i * 64 + lane]) * di * di;
  int e0 = rs[i], e1 = rs[i + 1];
  int e = e0;
  for (; e + 4 <= e1; e += 4) {
    int s0 = es[e], s1 = es[e + 1], s2 = es[e + 2], s3 = es[e + 3];
    float w0 = ew[e], w1 = ew[e + 1], w2 = ew[e + 2], w3 = ew[e + 3];
    float v0 = bf2f(h[(size_t)s0 * 64 + lane]);
    float v1 = bf2f(h[(size_t)s1 * 64 + lane]);
    float v2 = bf2f(h[(size_t)s2 * 64 + lane]);
    float v3 = bf2f(h[(size_t)s3 * 64 + lane]);
    acc += v0 * w0 + v1 * w1 + v2 * w2 + v3 * w3;
  }
  for (; e < e1; e++) {
    acc += bf2f(h[(size_t)es[e] * 64 + lane]) * ew[e];
  }
  acc += bias[lane];
  float m = acc;
#pragma unroll
  for (int off = 32; off > 0; off >>= 1) m = fmaxf(m, __shfl_xor(m, off));
  float ex = __expf(acc - m);
  float sum = ex;
#pragma unroll
  for (int off = 32; off > 0; off >>= 1) sum += __shfl_xor(sum, off);
  float p = ex / sum;
  float e2 = __expf(p);
  float s2 = e2;
#pragma unroll
  for (int off = 32; off > 0; off >>= 1) s2 += __shfl_xor(s2, off);
  out[(size_t)i * 64 + lane] = p - __logf(s2);
}

// ---------- launch ----------
extern "C" void kernel_launch(void* const* d_in, const int* in_sizes, int n_in,
                              void* d_out, int out_size, void* d_ws, size_t ws_size,
                              hipStream_t stream) {
  const float* x    = (const float*)d_in[0];
  const int*   eidx = (const int*)d_in[1];
  const float* W1   = (const float*)d_in[2];
  const float* b1   = (const float*)d_in[3];
  const float* W2   = (const float*)d_in[4];
  const float* b2   = (const float*)d_in[5];
  const float* W3   = (const float*)d_in[6];
  const float* b3   = (const float*)d_in[7];
  float* out = (float*)d_out;

  const int E = in_sizes[1] / 2;            // 800000
  const int* src = eidx;
  const int* dst = eidx + E;

  char* p = (char*)d_ws;
  auto alloc = [&](size_t bytes) -> void* {
    void* r = (void*)p;
    p += (bytes + 255) & ~(size_t)255;
    return r;
  };
  unsigned short* xb  = (unsigned short*)alloc((size_t)MPAD * 512 * 2);
  unsigned short* hb  = (unsigned short*)alloc((size_t)MPAD * 256 * 2);
  unsigned short* ab  = (unsigned short*)alloc((size_t)MPAD * 256 * 2);
  unsigned short* h3  = (unsigned short*)alloc((size_t)MPAD * 64 * 2);
  unsigned short* W1T = (unsigned short*)alloc((size_t)256 * 512 * 2);
  unsigned short* W2T = (unsigned short*)alloc((size_t)256 * 256 * 2);
  unsigned short* W3T = (unsigned short*)alloc((size_t)64 * 256 * 2);
  int*   cnt  = (int*)alloc((size_t)NN * 4);
  int*   rs   = (int*)alloc((size_t)(NN + 1) * 4);
  int*   cur  = (int*)alloc((size_t)NN * 4);
  float* dinv = (float*)alloc((size_t)NN * 4);
  int*   es   = (int*)alloc((size_t)E * 4);
  float* ew   = (float*)alloc((size_t)E * 4);
  int*   bsum = (int*)alloc((size_t)SCAN_BLOCKS * 4);

  gcn_zero_k<<<(NN + 255) / 256, 256, 0, stream>>>(cnt, NN);
  gcn_count_k<<<(E + 255) / 256, 256, 0, stream>>>(dst, cnt, E);
  gcn_scan_blocks_k<<<SCAN_BLOCKS, 256, 0, stream>>>(cnt, bsum, NN);
  gcn_scan_tops_k<<<1, 256, 0, stream>>>(bsum, SCAN_BLOCKS);
  gcn_scan_final_k<<<SCAN_BLOCKS, 256, 0, stream>>>(cnt, bsum, rs, cur, dinv, NN, E);
  gcn_scatter_k<<<(E + 255) / 256, 256, 0, stream>>>(src, dst, cur, dinv, es, ew, E);

  gcn_cvt_x_k<<<((MPAD * 512 / 4) + 255) / 256, 256, 0, stream>>>(x, xb, MPAD, 512, NN);
  gcn_cvt_wT_k<<<(256 * 512 + 255) / 256, 256, 0, stream>>>(W1, W1T, 512, 256);
  gcn_cvt_wT_k<<<(256 * 256 + 255) / 256, 256, 0, stream>>>(W2, W2T, 256, 256);
  gcn_cvt_wT_k<<<(64 * 256 + 255) / 256, 256, 0, stream>>>(W3, W3T, 256, 64);

  const int MB = MPAD / 128;  // 391
  gcn_gemm_k<128, 4><<<dim3(MB, 2), 256, 0, stream>>>(xb, W1T, hb, 512, 256);
  gcn_agg_relu_k<256><<<(NN + 3) / 4, 256, 0, stream>>>(hb, rs, es, ew, dinv, b1, ab, NN);
  gcn_gemm_k<128, 4><<<dim3(MB, 2), 256, 0, stream>>>(ab, W2T, hb, 256, 256);
  gcn_agg_relu_k<256><<<(NN + 3) / 4, 256, 0, stream>>>(hb, rs, es, ew, dinv, b2, ab, NN);
  gcn_gemm_k<64, 2><<<dim3(MB, 1), 256, 0, stream>>>(ab, W3T, h3, 256, 64);
  gcn_agg_final_k<<<(NN + 3) / 4, 256, 0, stream>>>(h3, rs, es, ew, dinv, b3, out, NN);

  (void)n_in; (void)out_size; (void)ws_size;
}

// Round 4
// 486.834 us; speedup vs baseline: 1.6603x; 1.0714x over previous
//
#include <hip/hip_runtime.h>
#include <cstdint>
#include <cstddef>

// ---------- types / helpers ----------
typedef float  f32x4  __attribute__((ext_vector_type(4)));
typedef __bf16 bf16x8 __attribute__((ext_vector_type(8)));
typedef unsigned short u16x8 __attribute__((ext_vector_type(8)));
typedef unsigned short u16x4 __attribute__((ext_vector_type(4)));

__device__ __forceinline__ unsigned short f2bf(float f) {
  union { float f; unsigned int u; } v; v.f = f;
  unsigned int r = v.u + 0x7fffu + ((v.u >> 16) & 1u);   // RNE
  return (unsigned short)(r >> 16);
}
__device__ __forceinline__ float bf2f(unsigned short h) {
  union { unsigned int u; float f; } v; v.u = ((unsigned int)h) << 16;
  return v.f;
}

// async global->LDS, 16B per lane. LDS dest must be lane-contiguous in wave order.
__device__ __forceinline__ void async_copy16(const unsigned short* g, unsigned short* l) {
  __builtin_amdgcn_global_load_lds(
      (const __attribute__((address_space(1))) unsigned int*)g,
      (__attribute__((address_space(3))) unsigned int*)l, 16, 0, 0);
}

#define NN 50000
#define MPAD 50048       // 391 * 128
#define SCAN_BLOCKS 196  // ceil(50000/256)

// ---------- graph prep ----------
__global__ void gcn_zero_k(int* __restrict__ p, int n) {
  int i = blockIdx.x * 256 + threadIdx.x;
  if (i < n) p[i] = 0;
}

__global__ void gcn_count_k(const int* __restrict__ dst, int* __restrict__ cnt, int E) {
  int e = blockIdx.x * 256 + threadIdx.x;
  if (e < E) atomicAdd(&cnt[dst[e]], 1);
}

__global__ __launch_bounds__(256) void gcn_scan_blocks_k(
    const int* __restrict__ cnt, int* __restrict__ blockSum, int nNodes) {
  __shared__ int sw[4];
  int t = threadIdx.x;
  int i = blockIdx.x * 256 + t;
  int v = (i < nNodes) ? cnt[i] : 0;
  for (int off = 32; off > 0; off >>= 1) v += __shfl_down(v, off);
  if ((t & 63) == 0) sw[t >> 6] = v;
  __syncthreads();
  if (t == 0) blockSum[blockIdx.x] = sw[0] + sw[1] + sw[2] + sw[3];
}

__global__ __launch_bounds__(256) void gcn_scan_tops_k(
    int* __restrict__ blockSum, int nBlocks) {
  __shared__ int sb[256];
  int t = threadIdx.x;
  int v = (t < nBlocks) ? blockSum[t] : 0;
  sb[t] = v;
  __syncthreads();
  for (int off = 1; off < 256; off <<= 1) {
    int x = (t >= off) ? sb[t - off] : 0;
    __syncthreads();
    sb[t] += x;
    __syncthreads();
  }
  if (t < nBlocks) blockSum[t] = sb[t] - v;  // exclusive
}

__global__ __launch_bounds__(256) void gcn_scan_final_k(
    const int* __restrict__ cnt, const int* __restrict__ blockSum,
    int* __restrict__ rs, int* __restrict__ cur, float* __restrict__ dinv,
    int nNodes, int E) {
  __shared__ int sb[256];
  int t = threadIdx.x;
  int i = blockIdx.x * 256 + t;
  int v = (i < nNodes) ? cnt[i] : 0;
  sb[t] = v;
  __syncthreads();
  for (int off = 1; off < 256; off <<= 1) {
    int x = (t >= off) ? sb[t - off] : 0;
    __syncthreads();
    sb[t] += x;
    __syncthreads();
  }
  if (i < nNodes) {
    int off = blockSum[blockIdx.x] + sb[t] - v;
    rs[i] = off; cur[i] = off;
    dinv[i] = rsqrtf(1.0f + (float)v);
  }
  if (i == 0) rs[nNodes] = E;
}

// scatter edges sorted by dst; pack (src, norm) into one int2
__global__ void gcn_scatter_k(const int* __restrict__ src, const int* __restrict__ dst,
                              int* __restrict__ cur, const float* __restrict__ dinv,
                              int2* __restrict__ e2, int E) {
  int e = blockIdx.x * 256 + threadIdx.x;
  if (e < E) {
    int d = dst[e];
    int s = src[e];
    int p = atomicAdd(&cur[d], 1);
    int2 v; v.x = s; v.y = __float_as_int(dinv[s] * dinv[d]);
    e2[p] = v;
  }
}

// ---------- weight conversion (all three, one launch) ----------
__global__ void gcn_cvt_w_all_k(const float* __restrict__ W1, const float* __restrict__ W2,
                                const float* __restrict__ W3,
                                unsigned short* __restrict__ W1T,
                                unsigned short* __restrict__ W2T,
                                unsigned short* __restrict__ W3T) {
  int idx = blockIdx.x * 256 + threadIdx.x;
  if (idx < 131072) {                       // W1 [512x256] -> W1T [256x512]
    int n = idx / 512, k = idx % 512;
    W1T[idx] = f2bf(W1[(size_t)k * 256 + n]);
  } else if (idx < 196608) {                // W2 [256x256] -> W2T [256x256]
    int j = idx - 131072; int n = j / 256, k = j % 256;
    W2T[j] = f2bf(W2[(size_t)k * 256 + n]);
  } else if (idx < 212992) {                // W3 [256x64] -> W3T [64x256]
    int j = idx - 196608; int n = j / 256, k = j % 256;
    W3T[j] = f2bf(W3[(size_t)k * 64 + n]);
  }
}

// swizzled chunk position: breaks LDS bank aliasing down to free 2-way
__device__ __forceinline__ int swz(int c4, int r) {
  return c4 ^ (r & 3) ^ ((r >> 2) & 3);
}

// ---------- GEMM1: C = cvt_bf16(X_f32) @ W1T^T, BN=256, fused conversion ----------
__global__ __launch_bounds__(256) void gcn_gemm_x_k(
    const float* __restrict__ X,            // [NN x 512] f32
    const unsigned short* __restrict__ Bt,  // [256 x 512] bf16
    unsigned short* __restrict__ C,         // [MPAD x 256] bf16
    int K, int N, int validRows) {
  constexpr int BN = 256, WTN = 8;
  __shared__ __align__(16) unsigned short lds_a[128 * 32];
  __shared__ __align__(16) unsigned short lds_b[BN * 32];
  const int t = threadIdx.x;
  const int wave = t >> 6, lane = t & 63;
  const int wr = wave >> 1, wc = wave & 1;
  const int quad = lane >> 4, lrow = lane & 15;
  const int m0 = blockIdx.x * 128;

  f32x4 acc[4][WTN] = {};

  for (int k0 = 0; k0 < K; k0 += 32) {
    __syncthreads();
    // A: convert f32 -> bf16 in VGPR, swizzled ds_write
    for (int q = t; q < 512; q += 256) {
      int r = q >> 2, c4 = q & 3;
      u16x8 o;
      if (m0 + r < validRows) {
        const float* srcp = &X[(size_t)(m0 + r) * K + k0 + c4 * 8];
        float4 v0 = *(const float4*)srcp;
        float4 v1 = *(const float4*)(srcp + 4);
        o[0] = f2bf(v0.x); o[1] = f2bf(v0.y); o[2] = f2bf(v0.z); o[3] = f2bf(v0.w);
        o[4] = f2bf(v1.x); o[5] = f2bf(v1.y); o[6] = f2bf(v1.z); o[7] = f2bf(v1.w);
      } else {
        o = u16x8{0, 0, 0, 0, 0, 0, 0, 0};
      }
      *(u16x8*)&lds_a[(r * 4 + swz(c4, r)) * 8] = o;
    }
    // B: async 16B, source-swizzled so LDS dest stays lane-contiguous
    for (int q = t; q < BN * 4; q += 256) {
      int r = q >> 2, c4 = swz(q & 3, r);
      async_copy16(&Bt[(size_t)r * K + k0 + c4 * 8], &lds_b[q * 8]);
    }
    __syncthreads();
    bf16x8 af[4], bfr[WTN];
#pragma unroll
    for (int mt = 0; mt < 4; mt++) {
      int R = wr * 64 + mt * 16 + lrow;
      af[mt] = *(const bf16x8*)&lds_a[R * 32 + swz(quad, R) * 8];
    }
#pragma unroll
    for (int nt = 0; nt < WTN; nt++) {
      int R = wc * (BN / 2) + nt * 16 + lrow;
      bfr[nt] = *(const bf16x8*)&lds_b[R * 32 + swz(quad, R) * 8];
    }
#pragma unroll
    for (int mt = 0; mt < 4; mt++)
#pragma unroll
      for (int nt = 0; nt < WTN; nt++)
        acc[mt][nt] = __builtin_amdgcn_mfma_f32_16x16x32_bf16(af[mt], bfr[nt], acc[mt][nt], 0, 0, 0);
  }

#pragma unroll
  for (int mt = 0; mt < 4; mt++)
#pragma unroll
    for (int nt = 0; nt < WTN; nt++)
#pragma unroll
      for (int r = 0; r < 4; r++) {
        int row = m0 + wr * 64 + mt * 16 + quad * 4 + r;
        int col = wc * (BN / 2) + nt * 16 + lrow;
        C[(size_t)row * N + col] = f2bf(acc[mt][nt][r]);
      }
}

// ---------- bf16 GEMM (A and B both async-staged): C = A @ Bt^T ----------
template<int BN, int WTN>
__global__ __launch_bounds__(256) void gcn_gemm_k(
    const unsigned short* __restrict__ A,   // [MPAD x K] bf16
    const unsigned short* __restrict__ Bt,  // [BN x K]   bf16
    unsigned short* __restrict__ C,         // [MPAD x BN] bf16
    int K, int N) {
  __shared__ __align__(16) unsigned short lds_a[128 * 32];
  __shared__ __align__(16) unsigned short lds_b[BN * 32];
  const int t = threadIdx.x;
  const int wave = t >> 6, lane = t & 63;
  const int wr = wave >> 1, wc = wave & 1;
  const int quad = lane >> 4, lrow = lane & 15;
  const int m0 = blockIdx.x * 128;

  f32x4 acc[4][WTN] = {};

  for (int k0 = 0; k0 < K; k0 += 32) {
    __syncthreads();
    for (int q = t; q < 512; q += 256) {
      int r = q >> 2, c4 = swz(q & 3, r);
      async_copy16(&A[(size_t)(m0 + r) * K + k0 + c4 * 8], &lds_a[q * 8]);
    }
    for (int q = t; q < BN * 4; q += 256) {
      int r = q >> 2, c4 = swz(q & 3, r);
      async_copy16(&Bt[(size_t)r * K + k0 + c4 * 8], &lds_b[q * 8]);
    }
    __syncthreads();
    bf16x8 af[4], bfr[WTN];
#pragma unroll
    for (int mt = 0; mt < 4; mt++) {
      int R = wr * 64 + mt * 16 + lrow;
      af[mt] = *(const bf16x8*)&lds_a[R * 32 + swz(quad, R) * 8];
    }
#pragma unroll
    for (int nt = 0; nt < WTN; nt++) {
      int R = wc * (BN / 2) + nt * 16 + lrow;
      bfr[nt] = *(const bf16x8*)&lds_b[R * 32 + swz(quad, R) * 8];
    }
#pragma unroll
    for (int mt = 0; mt < 4; mt++)
#pragma unroll
      for (int nt = 0; nt < WTN; nt++)
        acc[mt][nt] = __builtin_amdgcn_mfma_f32_16x16x32_bf16(af[mt], bfr[nt], acc[mt][nt], 0, 0, 0);
  }

#pragma unroll
  for (int mt = 0; mt < 4; mt++)
#pragma unroll
    for (int nt = 0; nt < WTN; nt++)
#pragma unroll
      for (int r = 0; r < 4; r++) {
        int row = m0 + wr * 64 + mt * 16 + quad * 4 + r;
        int col = wc * (BN / 2) + nt * 16 + lrow;
        C[(size_t)row * N + col] = f2bf(acc[mt][nt][r]);
      }
}

// ---------- aggregation, fused bias+self+ReLU, bf16 out ----------
// 2 edges per wave (32 lanes x u16x8 per row), unroll x4 -> 8 edges in flight.
template<int D>  // D = 256
__global__ __launch_bounds__(256) void gcn_agg_relu_k(
    const unsigned short* __restrict__ h, const int* __restrict__ rs,
    const int2* __restrict__ e2, const float* __restrict__ dinv,
    const float* __restrict__ bias, unsigned short* __restrict__ out, int nNodes) {
  int wave = threadIdx.x >> 6, lane = threadIdx.x & 63;
  int i = blockIdx.x * 4 + wave;
  if (i >= nNodes) return;
  int half = lane >> 5, sub = lane & 31;
  int f0 = sub * 8;
  float di = dinv[i];
  u16x8 hv = *(const u16x8*)&h[(size_t)i * D + f0];
  float wself = (half == 0) ? di * di : 0.0f;
  float acc[8];
#pragma unroll
  for (int j = 0; j < 8; j++) acc[j] = bf2f(hv[j]) * wself;

  int e0 = rs[i], e1 = rs[i + 1];
  int nIter = (e1 - e0 + 7) >> 3;
  int e = e0 + half;
  for (int k = 0; k < nIter; k++) {
    int idx[4]; float w[4];
#pragma unroll
    for (int u = 0; u < 4; u++) {
      int ee = e + 2 * u;
      bool v = ee < e1;
      int2 pr = e2[v ? ee : e0];
      idx[u] = v ? pr.x : i;
      w[u] = v ? __int_as_float(pr.y) : 0.0f;
    }
    u16x8 r0 = *(const u16x8*)&h[(size_t)idx[0] * D + f0];
    u16x8 r1 = *(const u16x8*)&h[(size_t)idx[1] * D + f0];
    u16x8 r2 = *(const u16x8*)&h[(size_t)idx[2] * D + f0];
    u16x8 r3 = *(const u16x8*)&h[(size_t)idx[3] * D + f0];
#pragma unroll
    for (int j = 0; j < 8; j++)
      acc[j] += bf2f(r0[j]) * w[0] + bf2f(r1[j]) * w[1] +
                bf2f(r2[j]) * w[2] + bf2f(r3[j]) * w[3];
    e += 8;
  }
#pragma unroll
  for (int j = 0; j < 8; j++) acc[j] += __shfl_xor(acc[j], 32);
  if (half == 0) {
    u16x8 o;
#pragma unroll
    for (int j = 0; j < 8; j++) {
      float r = acc[j] + bias[f0 + j];
      o[j] = f2bf(r > 0.0f ? r : 0.0f);
    }
    *(u16x8*)&out[(size_t)i * D + f0] = o;
  }
}

// final layer: D=64; 4 edges per wave (16 lanes x u16x4), fused softmax+log_softmax
__global__ __launch_bounds__(256) void gcn_agg_final_k(
    const unsigned short* __restrict__ h, const int* __restrict__ rs,
    const int2* __restrict__ e2, const float* __restrict__ dinv,
    const float* __restrict__ bias, float* __restrict__ out, int nNodes) {
  int wave = threadIdx.x >> 6, lane = threadIdx.x & 63;
  int i = blockIdx.x * 4 + wave;
  if (i >= nNodes) return;
  int qtr = lane >> 4, sub = lane & 15;
  int f0 = sub * 4;
  float di = dinv[i];
  u16x4 hv = *(const u16x4*)&h[(size_t)i * 64 + f0];
  float wself = (qtr == 0) ? di * di : 0.0f;
  float acc[4];
#pragma unroll
  for (int j = 0; j < 4; j++) acc[j] = bf2f(hv[j]) * wself;

  int e0 = rs[i], e1 = rs[i + 1];
  int nIter = (e1 - e0 + 7) >> 3;
  int e = e0 + qtr;
  for (int k = 0; k < nIter; k++) {
    int idx[2]; float w[2];
#pragma unroll
    for (int u = 0; u < 2; u++) {
      int ee = e + 4 * u;
      bool v = ee < e1;
      int2 pr = e2[v ? ee : e0];
      idx[u] = v ? pr.x : i;
      w[u] = v ? __int_as_float(pr.y) : 0.0f;
    }
    u16x4 r0 = *(const u16x4*)&h[(size_t)idx[0] * 64 + f0];
    u16x4 r1 = *(const u16x4*)&h[(size_t)idx[1] * 64 + f0];
#pragma unroll
    for (int j = 0; j < 4; j++)
      acc[j] += bf2f(r0[j]) * w[0] + bf2f(r1[j]) * w[1];
    e += 8;
  }
#pragma unroll
  for (int j = 0; j < 4; j++) {
    acc[j] += __shfl_xor(acc[j], 16);
    acc[j] += __shfl_xor(acc[j], 32);
    acc[j] += bias[f0 + j];
  }
  // softmax over the 64 features (spread over 16 lanes x 4 regs; all lanes hold full sums)
  float m = fmaxf(fmaxf(acc[0], acc[1]), fmaxf(acc[2], acc[3]));
#pragma unroll
  for (int off = 8; off > 0; off >>= 1) m = fmaxf(m, __shfl_xor(m, off));
  float ex[4], s = 0.0f;
#pragma unroll
  for (int j = 0; j < 4; j++) { ex[j] = __expf(acc[j] - m); s += ex[j]; }
#pragma unroll
  for (int off = 8; off > 0; off >>= 1) s += __shfl_xor(s, off);
  float rcs = 1.0f / s;
  float p[4], s2 = 0.0f;
#pragma unroll
  for (int j = 0; j < 4; j++) { p[j] = ex[j] * rcs; s2 += __expf(p[j]); }
#pragma unroll
  for (int off = 8; off > 0; off >>= 1) s2 += __shfl_xor(s2, off);
  float ls = __logf(s2);
  if (qtr == 0) {
    float4 o; o.x = p[0] - ls; o.y = p[1] - ls; o.z = p[2] - ls; o.w = p[3] - ls;
    *(float4*)&out[(size_t)i * 64 + f0] = o;
  }
}

// ---------- launch ----------
extern "C" void kernel_launch(void* const* d_in, const int* in_sizes, int n_in,
                              void* d_out, int out_size, void* d_ws, size_t ws_size,
                              hipStream_t stream) {
  const float* x    = (const float*)d_in[0];
  const int*   eidx = (const int*)d_in[1];
  const float* W1   = (const float*)d_in[2];
  const float* b1   = (const float*)d_in[3];
  const float* W2   = (const float*)d_in[4];
  const float* b2   = (const float*)d_in[5];
  const float* W3   = (const float*)d_in[6];
  const float* b3   = (const float*)d_in[7];
  float* out = (float*)d_out;

  const int E = in_sizes[1] / 2;            // 800000
  const int* src = eidx;
  const int* dst = eidx + E;

  char* p = (char*)d_ws;
  auto alloc = [&](size_t bytes) -> void* {
    void* r = (void*)p;
    p += (bytes + 255) & ~(size_t)255;
    return r;
  };
  unsigned short* hb  = (unsigned short*)alloc((size_t)MPAD * 256 * 2);  // gemm out
  unsigned short* ab  = (unsigned short*)alloc((size_t)MPAD * 256 * 2);  // agg+relu out
  unsigned short* h3  = (unsigned short*)alloc((size_t)MPAD * 64 * 2);
  unsigned short* W1T = (unsigned short*)alloc((size_t)256 * 512 * 2);
  unsigned short* W2T = (unsigned short*)alloc((size_t)256 * 256 * 2);
  unsigned short* W3T = (unsigned short*)alloc((size_t)64 * 256 * 2);
  int*   cnt  = (int*)alloc((size_t)NN * 4);
  int*   rs   = (int*)alloc((size_t)(NN + 1) * 4);
  int*   cur  = (int*)alloc((size_t)NN * 4);
  float* dinv = (float*)alloc((size_t)NN * 4);
  int2*  e2   = (int2*)alloc((size_t)E * 8);
  int*   bsum = (int*)alloc((size_t)SCAN_BLOCKS * 4);

  gcn_zero_k<<<(NN + 255) / 256, 256, 0, stream>>>(cnt, NN);
  gcn_count_k<<<(E + 255) / 256, 256, 0, stream>>>(dst, cnt, E);
  gcn_scan_blocks_k<<<SCAN_BLOCKS, 256, 0, stream>>>(cnt, bsum, NN);
  gcn_scan_tops_k<<<1, 256, 0, stream>>>(bsum, SCAN_BLOCKS);
  gcn_scan_final_k<<<SCAN_BLOCKS, 256, 0, stream>>>(cnt, bsum, rs, cur, dinv, NN, E);
  gcn_scatter_k<<<(E + 255) / 256, 256, 0, stream>>>(src, dst, cur, dinv, e2, E);
  gcn_cvt_w_all_k<<<832, 256, 0, stream>>>(W1, W2, W3, W1T, W2T, W3T);

  const int MB = MPAD / 128;  // 391
  // layer 1 (fused f32->bf16 conversion in A staging)
  gcn_gemm_x_k<<<MB, 256, 0, stream>>>(x, W1T, hb, 512, 256, NN);
  gcn_agg_relu_k<256><<<(NN + 3) / 4, 256, 0, stream>>>(hb, rs, e2, dinv, b1, ab, NN);
  // layer 2
  gcn_gemm_k<256, 8><<<MB, 256, 0, stream>>>(ab, W2T, hb, 256, 256);
  gcn_agg_relu_k<256><<<(NN + 3) / 4, 256, 0, stream>>>(hb, rs, e2, dinv, b2, ab, NN);
  // layer 3 + fused softmax/log_softmax
  gcn_gemm_k<64, 2><<<MB, 256, 0, stream>>>(ab, W3T, h3, 256, 64);
  gcn_agg_final_k<<<(NN + 3) / 4, 256, 0, stream>>>(h3, rs, e2, dinv, b3, out, NN);

  (void)n_in; (void)out_size; (void)ws_size;
}

// Round 5
// 466.983 us; speedup vs baseline: 1.7309x; 1.0425x over previous
//
#include <hip/hip_runtime.h>
#include <cstdint>
#include <cstddef>

// ---------- types / helpers ----------
typedef float  f32x4  __attribute__((ext_vector_type(4)));
typedef __bf16 bf16x8 __attribute__((ext_vector_type(8)));
typedef unsigned short u16x8 __attribute__((ext_vector_type(8)));
typedef unsigned short u16x4 __attribute__((ext_vector_type(4)));

__device__ __forceinline__ unsigned short f2bf(float f) {
  union { float f; unsigned int u; } v; v.f = f;
  unsigned int r = v.u + 0x7fffu + ((v.u >> 16) & 1u);   // RNE
  return (unsigned short)(r >> 16);
}
__device__ __forceinline__ float bf2f(unsigned short h) {
  union { unsigned int u; float f; } v; v.u = ((unsigned int)h) << 16;
  return v.f;
}

// async global->LDS, 16B per lane. LDS dest must be lane-contiguous in wave order.
__device__ __forceinline__ void async_copy16(const unsigned short* g, unsigned short* l) {
  __builtin_amdgcn_global_load_lds(
      (const __attribute__((address_space(1))) unsigned int*)g,
      (__attribute__((address_space(3))) unsigned int*)l, 16, 0, 0);
}

#define NN 50000
#define MPAD 50048       // 391 * 128
#define SCAN_BLOCKS 196  // ceil(50000/256)

// ---------- graph prep ----------
__global__ void gcn_zero_k(int* __restrict__ p, int n) {
  int i = blockIdx.x * 256 + threadIdx.x;
  if (i < n) p[i] = 0;
}

__global__ void gcn_count_k(const int* __restrict__ dst, int* __restrict__ cnt, int E) {
  int e = blockIdx.x * 256 + threadIdx.x;
  if (e < E) atomicAdd(&cnt[dst[e]], 1);
}

__global__ __launch_bounds__(256) void gcn_scan_blocks_k(
    const int* __restrict__ cnt, int* __restrict__ blockSum, int nNodes) {
  __shared__ int sw[4];
  int t = threadIdx.x;
  int i = blockIdx.x * 256 + t;
  int v = (i < nNodes) ? cnt[i] : 0;
  for (int off = 32; off > 0; off >>= 1) v += __shfl_down(v, off);
  if ((t & 63) == 0) sw[t >> 6] = v;
  __syncthreads();
  if (t == 0) blockSum[blockIdx.x] = sw[0] + sw[1] + sw[2] + sw[3];
}

__global__ __launch_bounds__(256) void gcn_scan_tops_k(
    int* __restrict__ blockSum, int nBlocks) {
  __shared__ int sb[256];
  int t = threadIdx.x;
  int v = (t < nBlocks) ? blockSum[t] : 0;
  sb[t] = v;
  __syncthreads();
  for (int off = 1; off < 256; off <<= 1) {
    int x = (t >= off) ? sb[t - off] : 0;
    __syncthreads();
    sb[t] += x;
    __syncthreads();
  }
  if (t < nBlocks) blockSum[t] = sb[t] - v;  // exclusive
}

__global__ __launch_bounds__(256) void gcn_scan_final_k(
    const int* __restrict__ cnt, const int* __restrict__ blockSum,
    int* __restrict__ rs, int* __restrict__ cur, float* __restrict__ dinv,
    int nNodes, int E) {
  __shared__ int sb[256];
  int t = threadIdx.x;
  int i = blockIdx.x * 256 + t;
  int v = (i < nNodes) ? cnt[i] : 0;
  sb[t] = v;
  __syncthreads();
  for (int off = 1; off < 256; off <<= 1) {
    int x = (t >= off) ? sb[t - off] : 0;
    __syncthreads();
    sb[t] += x;
    __syncthreads();
  }
  if (i < nNodes) {
    int off = blockSum[blockIdx.x] + sb[t] - v;
    rs[i] = off; cur[i] = off;
    dinv[i] = rsqrtf(1.0f + (float)v);
  }
  if (i == 0) rs[nNodes] = E;
}

// scatter edges sorted by dst; pack (src, norm) into one int2
__global__ void gcn_scatter_k(const int* __restrict__ src, const int* __restrict__ dst,
                              int* __restrict__ cur, const float* __restrict__ dinv,
                              int2* __restrict__ e2, int E) {
  int e = blockIdx.x * 256 + threadIdx.x;
  if (e < E) {
    int d = dst[e];
    int s = src[e];
    int p = atomicAdd(&cur[d], 1);
    int2 v; v.x = s; v.y = __float_as_int(dinv[s] * dinv[d]);
    e2[p] = v;
  }
}

// ---------- weight conversion (all three, one launch) ----------
__global__ void gcn_cvt_w_all_k(const float* __restrict__ W1, const float* __restrict__ W2,
                                const float* __restrict__ W3,
                                unsigned short* __restrict__ W1T,
                                unsigned short* __restrict__ W2T,
                                unsigned short* __restrict__ W3T) {
  int idx = blockIdx.x * 256 + threadIdx.x;
  if (idx < 131072) {                       // W1 [512x256] -> W1T [256x512]
    int n = idx / 512, k = idx % 512;
    W1T[idx] = f2bf(W1[(size_t)k * 256 + n]);
  } else if (idx < 196608) {                // W2 [256x256] -> W2T [256x256]
    int j = idx - 131072; int n = j / 256, k = j % 256;
    W2T[j] = f2bf(W2[(size_t)k * 256 + n]);
  } else if (idx < 212992) {                // W3 [256x64] -> W3T [64x256]
    int j = idx - 196608; int n = j / 256, k = j % 256;
    W3T[j] = f2bf(W3[(size_t)k * 64 + n]);
  }
}

// ---------- GEMM1: C = cvt_bf16(X_f32) @ W1T^T, fused conversion, 128x128 tile ----------
// Plain [row][32] LDS layout: measured conflict-free on gfx950 (round-3 PMC), do NOT swizzle.
__global__ __launch_bounds__(256) void gcn_gemm_x_k(
    const float* __restrict__ X,            // [NN x 512] f32
    const unsigned short* __restrict__ Bt,  // [256 x 512] bf16
    unsigned short* __restrict__ C,         // [MPAD x 256] bf16
    int K, int N, int validRows) {
  constexpr int BN = 128, WTN = 4;
  __shared__ __align__(16) unsigned short lds_a[128 * 32];
  __shared__ __align__(16) unsigned short lds_b[BN * 32];
  const int t = threadIdx.x;
  const int wave = t >> 6, lane = t & 63;
  const int wr = wave >> 1, wc = wave & 1;
  const int quad = lane >> 4, lrow = lane & 15;
  const int m0 = blockIdx.x * 128;
  const int n0 = blockIdx.y * BN;

  f32x4 acc[4][WTN] = {};

  for (int k0 = 0; k0 < K; k0 += 32) {
    __syncthreads();
    // A: convert f32 -> bf16 in VGPR, ds_write (plain layout)
    for (int q = t; q < 512; q += 256) {
      int r = q >> 2, c = (q & 3) * 8;
      u16x8 o;
      if (m0 + r < validRows) {
        const float* srcp = &X[(size_t)(m0 + r) * K + k0 + c];
        float4 v0 = *(const float4*)srcp;
        float4 v1 = *(const float4*)(srcp + 4);
        o[0] = f2bf(v0.x); o[1] = f2bf(v0.y); o[2] = f2bf(v0.z); o[3] = f2bf(v0.w);
        o[4] = f2bf(v1.x); o[5] = f2bf(v1.y); o[6] = f2bf(v1.z); o[7] = f2bf(v1.w);
      } else {
        o = u16x8{0, 0, 0, 0, 0, 0, 0, 0};
      }
      *(u16x8*)&lds_a[r * 32 + c] = o;
    }
    // B: async 16B/lane, plain layout (dest lane-contiguous)
    for (int q = t; q < BN * 4; q += 256) {
      int r = q >> 2, c = (q & 3) * 8;
      async_copy16(&Bt[(size_t)(n0 + r) * K + k0 + c], &lds_b[q * 8]);
    }
    __syncthreads();
    bf16x8 af[4], bfr[WTN];
#pragma unroll
    for (int mt = 0; mt < 4; mt++)
      af[mt] = *(const bf16x8*)&lds_a[(wr * 64 + mt * 16 + lrow) * 32 + quad * 8];
#pragma unroll
    for (int nt = 0; nt < WTN; nt++)
      bfr[nt] = *(const bf16x8*)&lds_b[(wc * (BN / 2) + nt * 16 + lrow) * 32 + quad * 8];
#pragma unroll
    for (int mt = 0; mt < 4; mt++)
#pragma unroll
      for (int nt = 0; nt < WTN; nt++)
        acc[mt][nt] = __builtin_amdgcn_mfma_f32_16x16x32_bf16(af[mt], bfr[nt], acc[mt][nt], 0, 0, 0);
  }

#pragma unroll
  for (int mt = 0; mt < 4; mt++)
#pragma unroll
    for (int nt = 0; nt < WTN; nt++)
#pragma unroll
      for (int r = 0; r < 4; r++) {
        int row = m0 + wr * 64 + mt * 16 + quad * 4 + r;
        int col = n0 + wc * (BN / 2) + nt * 16 + lrow;
        C[(size_t)row * N + col] = f2bf(acc[mt][nt][r]);
      }
}

// ---------- bf16 GEMM (A and B async-staged): C = A @ Bt^T, 128 x BN tile ----------
template<int BN, int WTN>
__global__ __launch_bounds__(256) void gcn_gemm_k(
    const unsigned short* __restrict__ A,   // [MPAD x K] bf16
    const unsigned short* __restrict__ Bt,  // [N x K]    bf16
    unsigned short* __restrict__ C,         // [MPAD x N] bf16
    int K, int N) {
  __shared__ __align__(16) unsigned short lds_a[128 * 32];
  __shared__ __align__(16) unsigned short lds_b[BN * 32];
  const int t = threadIdx.x;
  const int wave = t >> 6, lane = t & 63;
  const int wr = wave >> 1, wc = wave & 1;
  const int quad = lane >> 4, lrow = lane & 15;
  const int m0 = blockIdx.x * 128;
  const int n0 = blockIdx.y * BN;

  f32x4 acc[4][WTN] = {};

  for (int k0 = 0; k0 < K; k0 += 32) {
    __syncthreads();
    for (int q = t; q < 512; q += 256) {
      int r = q >> 2, c = (q & 3) * 8;
      async_copy16(&A[(size_t)(m0 + r) * K + k0 + c], &lds_a[q * 8]);
    }
    for (int q = t; q < BN * 4; q += 256) {
      int r = q >> 2, c = (q & 3) * 8;
      async_copy16(&Bt[(size_t)(n0 + r) * K + k0 + c], &lds_b[q * 8]);
    }
    __syncthreads();
    bf16x8 af[4], bfr[WTN];
#pragma unroll
    for (int mt = 0; mt < 4; mt++)
      af[mt] = *(const bf16x8*)&lds_a[(wr * 64 + mt * 16 + lrow) * 32 + quad * 8];
#pragma unroll
    for (int nt = 0; nt < WTN; nt++)
      bfr[nt] = *(const bf16x8*)&lds_b[(wc * (BN / 2) + nt * 16 + lrow) * 32 + quad * 8];
#pragma unroll
    for (int mt = 0; mt < 4; mt++)
#pragma unroll
      for (int nt = 0; nt < WTN; nt++)
        acc[mt][nt] = __builtin_amdgcn_mfma_f32_16x16x32_bf16(af[mt], bfr[nt], acc[mt][nt], 0, 0, 0);
  }

#pragma unroll
  for (int mt = 0; mt < 4; mt++)
#pragma unroll
    for (int nt = 0; nt < WTN; nt++)
#pragma unroll
      for (int r = 0; r < 4; r++) {
        int row = m0 + wr * 64 + mt * 16 + quad * 4 + r;
        int col = n0 + wc * (BN / 2) + nt * 16 + lrow;
        C[(size_t)row * N + col] = f2bf(acc[mt][nt][r]);
      }
}

// ---------- aggregation, fused bias+self+ReLU, bf16 out ----------
// 2 edges per wave (32 lanes x u16x8 per row), unroll x4 -> 8 edges in flight.
template<int D>  // D = 256
__global__ __launch_bounds__(256) void gcn_agg_relu_k(
    const unsigned short* __restrict__ h, const int* __restrict__ rs,
    const int2* __restrict__ e2, const float* __restrict__ dinv,
    const float* __restrict__ bias, unsigned short* __restrict__ out, int nNodes) {
  int wave = threadIdx.x >> 6, lane = threadIdx.x & 63;
  int i = blockIdx.x * 4 + wave;
  if (i >= nNodes) return;
  int half = lane >> 5, sub = lane & 31;
  int f0 = sub * 8;
  float di = dinv[i];
  u16x8 hv = *(const u16x8*)&h[(size_t)i * D + f0];
  float wself = (half == 0) ? di * di : 0.0f;
  float acc[8];
#pragma unroll
  for (int j = 0; j < 8; j++) acc[j] = bf2f(hv[j]) * wself;

  int e0 = rs[i], e1 = rs[i + 1];
  int nIter = (e1 - e0 + 7) >> 3;
  int e = e0 + half;
  for (int k = 0; k < nIter; k++) {
    int idx[4]; float w[4];
#pragma unroll
    for (int u = 0; u < 4; u++) {
      int ee = e + 2 * u;
      bool v = ee < e1;
      int2 pr = e2[v ? ee : e0];
      idx[u] = v ? pr.x : i;
      w[u] = v ? __int_as_float(pr.y) : 0.0f;
    }
    u16x8 r0 = *(const u16x8*)&h[(size_t)idx[0] * D + f0];
    u16x8 r1 = *(const u16x8*)&h[(size_t)idx[1] * D + f0];
    u16x8 r2 = *(const u16x8*)&h[(size_t)idx[2] * D + f0];
    u16x8 r3 = *(const u16x8*)&h[(size_t)idx[3] * D + f0];
#pragma unroll
    for (int j = 0; j < 8; j++)
      acc[j] += bf2f(r0[j]) * w[0] + bf2f(r1[j]) * w[1] +
                bf2f(r2[j]) * w[2] + bf2f(r3[j]) * w[3];
    e += 8;
  }
#pragma unroll
  for (int j = 0; j < 8; j++) acc[j] += __shfl_xor(acc[j], 32);
  if (half == 0) {
    u16x8 o;
#pragma unroll
    for (int j = 0; j < 8; j++) {
      float r = acc[j] + bias[f0 + j];
      o[j] = f2bf(r > 0.0f ? r : 0.0f);
    }
    *(u16x8*)&out[(size_t)i * D + f0] = o;
  }
}

// final layer: D=64; 4 edges per wave (16 lanes x u16x4), fused softmax+log_softmax
__global__ __launch_bounds__(256) void gcn_agg_final_k(
    const unsigned short* __restrict__ h, const int* __restrict__ rs,
    const int2* __restrict__ e2, const float* __restrict__ dinv,
    const float* __restrict__ bias, float* __restrict__ out, int nNodes) {
  int wave = threadIdx.x >> 6, lane = threadIdx.x & 63;
  int i = blockIdx.x * 4 + wave;
  if (i >= nNodes) return;
  int qtr = lane >> 4, sub = lane & 15;
  int f0 = sub * 4;
  float di = dinv[i];
  u16x4 hv = *(const u16x4*)&h[(size_t)i * 64 + f0];
  float wself = (qtr == 0) ? di * di : 0.0f;
  float acc[4];
#pragma unroll
  for (int j = 0; j < 4; j++) acc[j] = bf2f(hv[j]) * wself;

  int e0 = rs[i], e1 = rs[i + 1];
  int nIter = (e1 - e0 + 7) >> 3;
  int e = e0 + qtr;
  for (int k = 0; k < nIter; k++) {
    int idx[2]; float w[2];
#pragma unroll
    for (int u = 0; u < 2; u++) {
      int ee = e + 4 * u;
      bool v = ee < e1;
      int2 pr = e2[v ? ee : e0];
      idx[u] = v ? pr.x : i;
      w[u] = v ? __int_as_float(pr.y) : 0.0f;
    }
    u16x4 r0 = *(const u16x4*)&h[(size_t)idx[0] * 64 + f0];
    u16x4 r1 = *(const u16x4*)&h[(size_t)idx[1] * 64 + f0];
#pragma unroll
    for (int j = 0; j < 4; j++)
      acc[j] += bf2f(r0[j]) * w[0] + bf2f(r1[j]) * w[1];
    e += 8;
  }
#pragma unroll
  for (int j = 0; j < 4; j++) {
    acc[j] += __shfl_xor(acc[j], 16);
    acc[j] += __shfl_xor(acc[j], 32);
    acc[j] += bias[f0 + j];
  }
  // softmax over 64 features (16 lanes x 4 regs; all lanes hold full sums)
  float m = fmaxf(fmaxf(acc[0], acc[1]), fmaxf(acc[2], acc[3]));
#pragma unroll
  for (int off = 8; off > 0; off >>= 1) m = fmaxf(m, __shfl_xor(m, off));
  float ex[4], s = 0.0f;
#pragma unroll
  for (int j = 0; j < 4; j++) { ex[j] = __expf(acc[j] - m); s += ex[j]; }
#pragma unroll
  for (int off = 8; off > 0; off >>= 1) s += __shfl_xor(s, off);
  float rcs = 1.0f / s;
  float p[4], s2 = 0.0f;
#pragma unroll
  for (int j = 0; j < 4; j++) { p[j] = ex[j] * rcs; s2 += __expf(p[j]); }
#pragma unroll
  for (int off = 8; off > 0; off >>= 1) s2 += __shfl_xor(s2, off);
  float ls = __logf(s2);
  if (qtr == 0) {
    float4 o; o.x = p[0] - ls; o.y = p[1] - ls; o.z = p[2] - ls; o.w = p[3] - ls;
    *(float4*)&out[(size_t)i * 64 + f0] = o;
  }
}

// ---------- launch ----------
extern "C" void kernel_launch(void* const* d_in, const int* in_sizes, int n_in,
                              void* d_out, int out_size, void* d_ws, size_t ws_size,
                              hipStream_t stream) {
  const float* x    = (const float*)d_in[0];
  const int*   eidx = (const int*)d_in[1];
  const float* W1   = (const float*)d_in[2];
  const float* b1   = (const float*)d_in[3];
  const float* W2   = (const float*)d_in[4];
  const float* b2   = (const float*)d_in[5];
  const float* W3   = (const float*)d_in[6];
  const float* b3   = (const float*)d_in[7];
  float* out = (float*)d_out;

  const int E = in_sizes[1] / 2;            // 800000
  const int* src = eidx;
  const int* dst = eidx + E;

  char* p = (char*)d_ws;
  auto alloc = [&](size_t bytes) -> void* {
    void* r = (void*)p;
    p += (bytes + 255) & ~(size_t)255;
    return r;
  };
  unsigned short* hb  = (unsigned short*)alloc((size_t)MPAD * 256 * 2);  // gemm out
  unsigned short* ab  = (unsigned short*)alloc((size_t)MPAD * 256 * 2);  // agg+relu out
  unsigned short* h3  = (unsigned short*)alloc((size_t)MPAD * 64 * 2);
  unsigned short* W1T = (unsigned short*)alloc((size_t)256 * 512 * 2);
  unsigned short* W2T = (unsigned short*)alloc((size_t)256 * 256 * 2);
  unsigned short* W3T = (unsigned short*)alloc((size_t)64 * 256 * 2);
  int*   cnt  = (int*)alloc((size_t)NN * 4);
  int*   rs   = (int*)alloc((size_t)(NN + 1) * 4);
  int*   cur  = (int*)alloc((size_t)NN * 4);
  float* dinv = (float*)alloc((size_t)NN * 4);
  int2*  e2   = (int2*)alloc((size_t)E * 8);
  int*   bsum = (int*)alloc((size_t)SCAN_BLOCKS * 4);

  gcn_zero_k<<<(NN + 255) / 256, 256, 0, stream>>>(cnt, NN);
  gcn_count_k<<<(E + 255) / 256, 256, 0, stream>>>(dst, cnt, E);
  gcn_scan_blocks_k<<<SCAN_BLOCKS, 256, 0, stream>>>(cnt, bsum, NN);
  gcn_scan_tops_k<<<1, 256, 0, stream>>>(bsum, SCAN_BLOCKS);
  gcn_scan_final_k<<<SCAN_BLOCKS, 256, 0, stream>>>(cnt, bsum, rs, cur, dinv, NN, E);
  gcn_scatter_k<<<(E + 255) / 256, 256, 0, stream>>>(src, dst, cur, dinv, e2, E);
  gcn_cvt_w_all_k<<<832, 256, 0, stream>>>(W1, W2, W3, W1T, W2T, W3T);

  const int MB = MPAD / 128;  // 391
  // layer 1 (fused f32->bf16 conversion in A staging), 128x128 tiles, 782 blocks
  gcn_gemm_x_k<<<dim3(MB, 2), 256, 0, stream>>>(x, W1T, hb, 512, 256, NN);
  gcn_agg_relu_k<256><<<(NN + 3) / 4, 256, 0, stream>>>(hb, rs, e2, dinv, b1, ab, NN);
  // layer 2
  gcn_gemm_k<128, 4><<<dim3(MB, 2), 256, 0, stream>>>(ab, W2T, hb, 256, 256);
  gcn_agg_relu_k<256><<<(NN + 3) / 4, 256, 0, stream>>>(hb, rs, e2, dinv, b2, ab, NN);
  // layer 3 + fused softmax/log_softmax
  gcn_gemm_k<64, 2><<<dim3(MB, 1), 256, 0, stream>>>(ab, W3T, h3, 256, 64);
  gcn_agg_final_k<<<(NN + 3) / 4, 256, 0, stream>>>(h3, rs, e2, dinv, b3, out, NN);

  (void)n_in; (void)out_size; (void)ws_size;
}

// Round 6
// 466.607 us; speedup vs baseline: 1.7323x; 1.0008x over previous
//
#include <hip/hip_runtime.h>
#include <cstdint>
#include <cstddef>

// ---------- types / helpers ----------
typedef float  f32x4  __attribute__((ext_vector_type(4)));
typedef __bf16 bf16x8 __attribute__((ext_vector_type(8)));
typedef unsigned short u16x8 __attribute__((ext_vector_type(8)));
typedef unsigned short u16x4 __attribute__((ext_vector_type(4)));

__device__ __forceinline__ unsigned short f2bf(float f) {
  union { float f; unsigned int u; } v; v.f = f;
  unsigned int r = v.u + 0x7fffu + ((v.u >> 16) & 1u);   // RNE
  return (unsigned short)(r >> 16);
}
__device__ __forceinline__ float bf2f(unsigned short h) {
  union { unsigned int u; float f; } v; v.u = ((unsigned int)h) << 16;
  return v.f;
}

// async global->LDS, 16B per lane. LDS dest must be lane-contiguous in wave order.
__device__ __forceinline__ void async_copy16(const unsigned short* g, unsigned short* l) {
  __builtin_amdgcn_global_load_lds(
      (const __attribute__((address_space(1))) unsigned int*)g,
      (__attribute__((address_space(3))) unsigned int*)l, 16, 0, 0);
}

#define NN 50000
#define MPAD 50048       // 391 * 128
#define SCAN_BLOCKS 196  // ceil(50000/256)

// mega-prep block ranges
#define XB_BLOCKS 12512  // MPAD*512/8/256
#define ZB_BLOCKS 196    // zero cnt
#define WB_BLOCKS 104    // 212992/8/256

// ---------- mega prep: cvt X -> bf16 (padded), zero cnt, cvt all weights ----------
__global__ __launch_bounds__(256) void gcn_prep_k(
    const float* __restrict__ X, unsigned short* __restrict__ xb,
    int* __restrict__ cnt,
    const float* __restrict__ W1, const float* __restrict__ W2,
    const float* __restrict__ W3,
    unsigned short* __restrict__ W1T, unsigned short* __restrict__ W2T,
    unsigned short* __restrict__ W3T) {
  int b = blockIdx.x;
  if (b < XB_BLOCKS) {
    // X [NN x 512] f32 -> xb [MPAD x 512] bf16, 8 elems/thread
    int idx8 = (b * 256 + threadIdx.x) * 8;
    int row = idx8 >> 9;
    u16x8 o;
    if (row < NN) {
      const float* s = &X[idx8];
      float4 v0 = *(const float4*)s;
      float4 v1 = *(const float4*)(s + 4);
      o[0] = f2bf(v0.x); o[1] = f2bf(v0.y); o[2] = f2bf(v0.z); o[3] = f2bf(v0.w);
      o[4] = f2bf(v1.x); o[5] = f2bf(v1.y); o[6] = f2bf(v1.z); o[7] = f2bf(v1.w);
    } else {
      o = u16x8{0, 0, 0, 0, 0, 0, 0, 0};
    }
    *(u16x8*)&xb[idx8] = o;
  } else if (b < XB_BLOCKS + ZB_BLOCKS) {
    int i = (b - XB_BLOCKS) * 256 + threadIdx.x;
    if (i < NN) cnt[i] = 0;
  } else if (b < XB_BLOCKS + ZB_BLOCKS + WB_BLOCKS) {
    int idx8 = ((b - XB_BLOCKS - ZB_BLOCKS) * 256 + threadIdx.x) * 8;
    u16x8 o;
    if (idx8 < 131072) {                       // W1 [512x256] -> W1T [256x512]
#pragma unroll
      for (int j = 0; j < 8; j++) {
        int idx = idx8 + j; int n = idx >> 9, k = idx & 511;
        o[j] = f2bf(W1[(size_t)k * 256 + n]);
      }
      *(u16x8*)&W1T[idx8] = o;
    } else if (idx8 < 196608) {                // W2 [256x256] -> W2T [256x256]
      int j0 = idx8 - 131072;
#pragma unroll
      for (int j = 0; j < 8; j++) {
        int idx = j0 + j; int n = idx >> 8, k = idx & 255;
        o[j] = f2bf(W2[(size_t)k * 256 + n]);
      }
      *(u16x8*)&W2T[j0] = o;
    } else if (idx8 < 212992) {                // W3 [256x64] -> W3T [64x256]
      int j0 = idx8 - 196608;
#pragma unroll
      for (int j = 0; j < 8; j++) {
        int idx = j0 + j; int n = idx >> 8, k = idx & 255;
        o[j] = f2bf(W3[(size_t)k * 64 + n]);
      }
      *(u16x8*)&W3T[j0] = o;
    }
  }
}

// ---------- graph prep ----------
__global__ void gcn_count_k(const int* __restrict__ dst, int* __restrict__ cnt, int E) {
  int e = blockIdx.x * 256 + threadIdx.x;
  if (e < E) atomicAdd(&cnt[dst[e]], 1);
}

__global__ __launch_bounds__(256) void gcn_scan_blocks_k(
    const int* __restrict__ cnt, int* __restrict__ blockSum, int nNodes) {
  __shared__ int sw[4];
  int t = threadIdx.x;
  int i = blockIdx.x * 256 + t;
  int v = (i < nNodes) ? cnt[i] : 0;
  for (int off = 32; off > 0; off >>= 1) v += __shfl_down(v, off);
  if ((t & 63) == 0) sw[t >> 6] = v;
  __syncthreads();
  if (t == 0) blockSum[blockIdx.x] = sw[0] + sw[1] + sw[2] + sw[3];
}

__global__ __launch_bounds__(256) void gcn_scan_tops_k(
    int* __restrict__ blockSum, int nBlocks) {
  __shared__ int sb[256];
  int t = threadIdx.x;
  int v = (t < nBlocks) ? blockSum[t] : 0;
  sb[t] = v;
  __syncthreads();
  for (int off = 1; off < 256; off <<= 1) {
    int x = (t >= off) ? sb[t - off] : 0;
    __syncthreads();
    sb[t] += x;
    __syncthreads();
  }
  if (t < nBlocks) blockSum[t] = sb[t] - v;  // exclusive
}

__global__ __launch_bounds__(256) void gcn_scan_final_k(
    const int* __restrict__ cnt, const int* __restrict__ blockSum,
    int* __restrict__ rs, int* __restrict__ cur, float* __restrict__ dinv,
    int nNodes, int E) {
  __shared__ int sb[256];
  int t = threadIdx.x;
  int i = blockIdx.x * 256 + t;
  int v = (i < nNodes) ? cnt[i] : 0;
  sb[t] = v;
  __syncthreads();
  for (int off = 1; off < 256; off <<= 1) {
    int x = (t >= off) ? sb[t - off] : 0;
    __syncthreads();
    sb[t] += x;
    __syncthreads();
  }
  if (i < nNodes) {
    int off = blockSum[blockIdx.x] + sb[t] - v;
    rs[i] = off; cur[i] = off;
    dinv[i] = rsqrtf(1.0f + (float)v);
  }
  if (i == 0) rs[nNodes] = E;
}

// scatter edges sorted by dst; pack (src, norm) into one int2
__global__ void gcn_scatter_k(const int* __restrict__ src, const int* __restrict__ dst,
                              int* __restrict__ cur, const float* __restrict__ dinv,
                              int2* __restrict__ e2, int E) {
  int e = blockIdx.x * 256 + threadIdx.x;
  if (e < E) {
    int d = dst[e];
    int s = src[e];
    int p = atomicAdd(&cur[d], 1);
    int2 v; v.x = s; v.y = __float_as_int(dinv[s] * dinv[d]);
    e2[p] = v;
  }
}

// ---------- bf16 GEMM (A and B async-staged): C = A @ Bt^T, 128 x BN tile ----------
template<int BN, int WTN>
__global__ __launch_bounds__(256) void gcn_gemm_k(
    const unsigned short* __restrict__ A,   // [MPAD x K] bf16
    const unsigned short* __restrict__ Bt,  // [N x K]    bf16
    unsigned short* __restrict__ C,         // [MPAD x N] bf16
    int K, int N) {
  __shared__ __align__(16) unsigned short lds_a[128 * 32];
  __shared__ __align__(16) unsigned short lds_b[BN * 32];
  const int t = threadIdx.x;
  const int wave = t >> 6, lane = t & 63;
  const int wr = wave >> 1, wc = wave & 1;
  const int quad = lane >> 4, lrow = lane & 15;
  const int m0 = blockIdx.x * 128;
  const int n0 = blockIdx.y * BN;

  f32x4 acc[4][WTN] = {};

  for (int k0 = 0; k0 < K; k0 += 32) {
    __syncthreads();
    for (int q = t; q < 512; q += 256) {
      int r = q >> 2, c = (q & 3) * 8;
      async_copy16(&A[(size_t)(m0 + r) * K + k0 + c], &lds_a[q * 8]);
    }
    for (int q = t; q < BN * 4; q += 256) {
      int r = q >> 2, c = (q & 3) * 8;
      async_copy16(&Bt[(size_t)(n0 + r) * K + k0 + c], &lds_b[q * 8]);
    }
    __syncthreads();
    bf16x8 af[4], bfr[WTN];
#pragma unroll
    for (int mt = 0; mt < 4; mt++)
      af[mt] = *(const bf16x8*)&lds_a[(wr * 64 + mt * 16 + lrow) * 32 + quad * 8];
#pragma unroll
    for (int nt = 0; nt < WTN; nt++)
      bfr[nt] = *(const bf16x8*)&lds_b[(wc * (BN / 2) + nt * 16 + lrow) * 32 + quad * 8];
#pragma unroll
    for (int mt = 0; mt < 4; mt++)
#pragma unroll
      for (int nt = 0; nt < WTN; nt++)
        acc[mt][nt] = __builtin_amdgcn_mfma_f32_16x16x32_bf16(af[mt], bfr[nt], acc[mt][nt], 0, 0, 0);
  }

#pragma unroll
  for (int mt = 0; mt < 4; mt++)
#pragma unroll
    for (int nt = 0; nt < WTN; nt++)
#pragma unroll
      for (int r = 0; r < 4; r++) {
        int row = m0 + wr * 64 + mt * 16 + quad * 4 + r;
        int col = n0 + wc * (BN / 2) + nt * 16 + lrow;
        C[(size_t)row * N + col] = f2bf(acc[mt][nt][r]);
      }
}

// ---------- aggregation, fused bias+self+ReLU, bf16 out ----------
// 2 edges per wave (32 lanes x u16x8 per row), unroll x4 -> 8 edges in flight.
template<int D>  // D = 256
__global__ __launch_bounds__(256) void gcn_agg_relu_k(
    const unsigned short* __restrict__ h, const int* __restrict__ rs,
    const int2* __restrict__ e2, const float* __restrict__ dinv,
    const float* __restrict__ bias, unsigned short* __restrict__ out, int nNodes) {
  int wave = threadIdx.x >> 6, lane = threadIdx.x & 63;
  int i = blockIdx.x * 4 + wave;
  if (i >= nNodes) return;
  int half = lane >> 5, sub = lane & 31;
  int f0 = sub * 8;
  float di = dinv[i];
  u16x8 hv = *(const u16x8*)&h[(size_t)i * D + f0];
  float wself = (half == 0) ? di * di : 0.0f;
  float acc[8];
#pragma unroll
  for (int j = 0; j < 8; j++) acc[j] = bf2f(hv[j]) * wself;

  int e0 = rs[i], e1 = rs[i + 1];
  int nIter = (e1 - e0 + 7) >> 3;
  int e = e0 + half;
  for (int k = 0; k < nIter; k++) {
    int idx[4]; float w[4];
#pragma unroll
    for (int u = 0; u < 4; u++) {
      int ee = e + 2 * u;
      bool v = ee < e1;
      int2 pr = e2[v ? ee : e0];
      idx[u] = v ? pr.x : i;
      w[u] = v ? __int_as_float(pr.y) : 0.0f;
    }
    u16x8 r0 = *(const u16x8*)&h[(size_t)idx[0] * D + f0];
    u16x8 r1 = *(const u16x8*)&h[(size_t)idx[1] * D + f0];
    u16x8 r2 = *(const u16x8*)&h[(size_t)idx[2] * D + f0];
    u16x8 r3 = *(const u16x8*)&h[(size_t)idx[3] * D + f0];
#pragma unroll
    for (int j = 0; j < 8; j++)
      acc[j] += bf2f(r0[j]) * w[0] + bf2f(r1[j]) * w[1] +
                bf2f(r2[j]) * w[2] + bf2f(r3[j]) * w[3];
    e += 8;
  }
#pragma unroll
  for (int j = 0; j < 8; j++) acc[j] += __shfl_xor(acc[j], 32);
  if (half == 0) {
    u16x8 o;
#pragma unroll
    for (int j = 0; j < 8; j++) {
      float r = acc[j] + bias[f0 + j];
      o[j] = f2bf(r > 0.0f ? r : 0.0f);
    }
    *(u16x8*)&out[(size_t)i * D + f0] = o;
  }
}

// final layer: D=64; 4 edges per wave (16 lanes x u16x4), fused softmax+log_softmax
__global__ __launch_bounds__(256) void gcn_agg_final_k(
    const unsigned short* __restrict__ h, const int* __restrict__ rs,
    const int2* __restrict__ e2, const float* __restrict__ dinv,
    const float* __restrict__ bias, float* __restrict__ out, int nNodes) {
  int wave = threadIdx.x >> 6, lane = threadIdx.x & 63;
  int i = blockIdx.x * 4 + wave;
  if (i >= nNodes) return;
  int qtr = lane >> 4, sub = lane & 15;
  int f0 = sub * 4;
  float di = dinv[i];
  u16x4 hv = *(const u16x4*)&h[(size_t)i * 64 + f0];
  float wself = (qtr == 0) ? di * di : 0.0f;
  float acc[4];
#pragma unroll
  for (int j = 0; j < 4; j++) acc[j] = bf2f(hv[j]) * wself;

  int e0 = rs[i], e1 = rs[i + 1];
  int nIter = (e1 - e0 + 7) >> 3;
  int e = e0 + qtr;
  for (int k = 0; k < nIter; k++) {
    int idx[2]; float w[2];
#pragma unroll
    for (int u = 0; u < 2; u++) {
      int ee = e + 4 * u;
      bool v = ee < e1;
      int2 pr = e2[v ? ee : e0];
      idx[u] = v ? pr.x : i;
      w[u] = v ? __int_as_float(pr.y) : 0.0f;
    }
    u16x4 r0 = *(const u16x4*)&h[(size_t)idx[0] * 64 + f0];
    u16x4 r1 = *(const u16x4*)&h[(size_t)idx[1] * 64 + f0];
#pragma unroll
    for (int j = 0; j < 4; j++)
      acc[j] += bf2f(r0[j]) * w[0] + bf2f(r1[j]) * w[1];
    e += 8;
  }
#pragma unroll
  for (int j = 0; j < 4; j++) {
    acc[j] += __shfl_xor(acc[j], 16);
    acc[j] += __shfl_xor(acc[j], 32);
    acc[j] += bias[f0 + j];
  }
  // softmax over 64 features (16 lanes x 4 regs; all lanes hold full sums)
  float m = fmaxf(fmaxf(acc[0], acc[1]), fmaxf(acc[2], acc[3]));
#pragma unroll
  for (int off = 8; off > 0; off >>= 1) m = fmaxf(m, __shfl_xor(m, off));
  float ex[4], s = 0.0f;
#pragma unroll
  for (int j = 0; j < 4; j++) { ex[j] = __expf(acc[j] - m); s += ex[j]; }
#pragma unroll
  for (int off = 8; off > 0; off >>= 1) s += __shfl_xor(s, off);
  float rcs = 1.0f / s;
  float p[4], s2 = 0.0f;
#pragma unroll
  for (int j = 0; j < 4; j++) { p[j] = ex[j] * rcs; s2 += __expf(p[j]); }
#pragma unroll
  for (int off = 8; off > 0; off >>= 1) s2 += __shfl_xor(s2, off);
  float ls = __logf(s2);
  if (qtr == 0) {
    float4 o; o.x = p[0] - ls; o.y = p[1] - ls; o.z = p[2] - ls; o.w = p[3] - ls;
    *(float4*)&out[(size_t)i * 64 + f0] = o;
  }
}

// ---------- launch ----------
extern "C" void kernel_launch(void* const* d_in, const int* in_sizes, int n_in,
                              void* d_out, int out_size, void* d_ws, size_t ws_size,
                              hipStream_t stream) {
  const float* x    = (const float*)d_in[0];
  const int*   eidx = (const int*)d_in[1];
  const float* W1   = (const float*)d_in[2];
  const float* b1   = (const float*)d_in[3];
  const float* W2   = (const float*)d_in[4];
  const float* b2   = (const float*)d_in[5];
  const float* W3   = (const float*)d_in[6];
  const float* b3   = (const float*)d_in[7];
  float* out = (float*)d_out;

  const int E = in_sizes[1] / 2;            // 800000
  const int* src = eidx;
  const int* dst = eidx + E;

  char* p = (char*)d_ws;
  auto alloc = [&](size_t bytes) -> void* {
    void* r = (void*)p;
    p += (bytes + 255) & ~(size_t)255;
    return r;
  };
  unsigned short* xb  = (unsigned short*)alloc((size_t)MPAD * 512 * 2);
  unsigned short* hb  = (unsigned short*)alloc((size_t)MPAD * 256 * 2);  // gemm out
  unsigned short* ab  = (unsigned short*)alloc((size_t)MPAD * 256 * 2);  // agg+relu out
  unsigned short* h3  = (unsigned short*)alloc((size_t)MPAD * 64 * 2);
  unsigned short* W1T = (unsigned short*)alloc((size_t)256 * 512 * 2);
  unsigned short* W2T = (unsigned short*)alloc((size_t)256 * 256 * 2);
  unsigned short* W3T = (unsigned short*)alloc((size_t)64 * 256 * 2);
  int*   cnt  = (int*)alloc((size_t)NN * 4);
  int*   rs   = (int*)alloc((size_t)(NN + 1) * 4);
  int*   cur  = (int*)alloc((size_t)NN * 4);
  float* dinv = (float*)alloc((size_t)NN * 4);
  int2*  e2   = (int2*)alloc((size_t)E * 8);
  int*   bsum = (int*)alloc((size_t)SCAN_BLOCKS * 4);

  // mega prep: cvt X, zero cnt, cvt weights (one streaming launch)
  gcn_prep_k<<<XB_BLOCKS + ZB_BLOCKS + WB_BLOCKS, 256, 0, stream>>>(
      x, xb, cnt, W1, W2, W3, W1T, W2T, W3T);
  gcn_count_k<<<(E + 255) / 256, 256, 0, stream>>>(dst, cnt, E);
  gcn_scan_blocks_k<<<SCAN_BLOCKS, 256, 0, stream>>>(cnt, bsum, NN);
  gcn_scan_tops_k<<<1, 256, 0, stream>>>(bsum, SCAN_BLOCKS);
  gcn_scan_final_k<<<SCAN_BLOCKS, 256, 0, stream>>>(cnt, bsum, rs, cur, dinv, NN, E);
  gcn_scatter_k<<<(E + 255) / 256, 256, 0, stream>>>(src, dst, cur, dinv, e2, E);

  const int MB = MPAD / 128;  // 391
  // layer 1 (pure bf16, async staging end-to-end)
  gcn_gemm_k<128, 4><<<dim3(MB, 2), 256, 0, stream>>>(xb, W1T, hb, 512, 256);
  gcn_agg_relu_k<256><<<(NN + 3) / 4, 256, 0, stream>>>(hb, rs, e2, dinv, b1, ab, NN);
  // layer 2
  gcn_gemm_k<128, 4><<<dim3(MB, 2), 256, 0, stream>>>(ab, W2T, hb, 256, 256);
  gcn_agg_relu_k<256><<<(NN + 3) / 4, 256, 0, stream>>>(hb, rs, e2, dinv, b2, ab, NN);
  // layer 3 + fused softmax/log_softmax
  gcn_gemm_k<64, 2><<<dim3(MB, 1), 256, 0, stream>>>(ab, W3T, h3, 256, 64);
  gcn_agg_final_k<<<(NN + 3) / 4, 256, 0, stream>>>(h3, rs, e2, dinv, b3, out, NN);

  (void)n_in; (void)out_size; (void)ws_size;
}

// Round 7
// 418.592 us; speedup vs baseline: 1.9310x; 1.1147x over previous
//
#include <hip/hip_runtime.h>
#include <cstdint>
#include <cstddef>

// ---------- types / helpers ----------
typedef float  f32x4  __attribute__((ext_vector_type(4)));
typedef float  f32x2  __attribute__((ext_vector_type(2)));
typedef __bf16 bf16x8 __attribute__((ext_vector_type(8)));
typedef unsigned short u16x8 __attribute__((ext_vector_type(8)));
typedef unsigned short u16x4 __attribute__((ext_vector_type(4)));

__device__ __forceinline__ unsigned short f2bf(float f) {
  union { float f; unsigned int u; } v; v.f = f;
  unsigned int r = v.u + 0x7fffu + ((v.u >> 16) & 1u);   // RNE
  return (unsigned short)(r >> 16);
}
__device__ __forceinline__ float bf2f(unsigned short h) {
  union { unsigned int u; float f; } v; v.u = ((unsigned int)h) << 16;
  return v.f;
}
// f32 -> fp8 e4m3 (OCP), HW convert, saturating
__device__ __forceinline__ unsigned char f2fp8(float f) {
  return (unsigned char)(__builtin_amdgcn_cvt_pk_fp8_f32(f, f, 0, false) & 0xff);
}
// decode 8 fp8 (packed in uint2) -> 8 floats
__device__ __forceinline__ void fp8x8_to_f32(uint2 d, float* f) {
  f32x2 a = __builtin_amdgcn_cvt_pk_f32_fp8((int)d.x, false);
  f32x2 b = __builtin_amdgcn_cvt_pk_f32_fp8((int)d.x, true);
  f32x2 c = __builtin_amdgcn_cvt_pk_f32_fp8((int)d.y, false);
  f32x2 e = __builtin_amdgcn_cvt_pk_f32_fp8((int)d.y, true);
  f[0] = a.x; f[1] = a.y; f[2] = b.x; f[3] = b.y;
  f[4] = c.x; f[5] = c.y; f[6] = e.x; f[7] = e.y;
}
__device__ __forceinline__ void fp8x4_to_f32(unsigned int d, float* f) {
  f32x2 a = __builtin_amdgcn_cvt_pk_f32_fp8((int)d, false);
  f32x2 b = __builtin_amdgcn_cvt_pk_f32_fp8((int)d, true);
  f[0] = a.x; f[1] = a.y; f[2] = b.x; f[3] = b.y;
}

// async global->LDS, 16B per lane. LDS dest must be lane-contiguous in wave order.
__device__ __forceinline__ void async_copy16(const unsigned short* g, unsigned short* l) {
  __builtin_amdgcn_global_load_lds(
      (const __attribute__((address_space(1))) unsigned int*)g,
      (__attribute__((address_space(3))) unsigned int*)l, 16, 0, 0);
}

#define NN 50000
#define MPAD 50048       // 391 * 128
#define SCAN_BLOCKS 196  // ceil(50000/256)

// prep block ranges (count blocks appended at runtime)
#define XB_BLOCKS 12512  // MPAD*512/8/256
#define WB_BLOCKS 104    // 212992/8/256

__global__ void gcn_zero_k(int* __restrict__ p, int n) {
  int i = blockIdx.x * 256 + threadIdx.x;
  if (i < n) p[i] = 0;
}

// ---------- mega prep: cvt X -> bf16 (padded), cvt weights, count degrees ----------
__global__ __launch_bounds__(256) void gcn_prep_k(
    const float* __restrict__ X, unsigned short* __restrict__ xb,
    const float* __restrict__ W1, const float* __restrict__ W2,
    const float* __restrict__ W3,
    unsigned short* __restrict__ W1T, unsigned short* __restrict__ W2T,
    unsigned short* __restrict__ W3T,
    const int* __restrict__ dst, int* __restrict__ cnt, int E) {
  int b = blockIdx.x;
  if (b < XB_BLOCKS) {
    // X [NN x 512] f32 -> xb [MPAD x 512] bf16, 8 elems/thread
    int idx8 = (b * 256 + threadIdx.x) * 8;
    int row = idx8 >> 9;
    u16x8 o;
    if (row < NN) {
      const float* s = &X[idx8];
      float4 v0 = *(const float4*)s;
      float4 v1 = *(const float4*)(s + 4);
      o[0] = f2bf(v0.x); o[1] = f2bf(v0.y); o[2] = f2bf(v0.z); o[3] = f2bf(v0.w);
      o[4] = f2bf(v1.x); o[5] = f2bf(v1.y); o[6] = f2bf(v1.z); o[7] = f2bf(v1.w);
    } else {
      o = u16x8{0, 0, 0, 0, 0, 0, 0, 0};
    }
    *(u16x8*)&xb[idx8] = o;
  } else if (b < XB_BLOCKS + WB_BLOCKS) {
    int idx8 = ((b - XB_BLOCKS) * 256 + threadIdx.x) * 8;
    u16x8 o;
    if (idx8 < 131072) {                       // W1 [512x256] -> W1T [256x512]
#pragma unroll
      for (int j = 0; j < 8; j++) {
        int idx = idx8 + j; int n = idx >> 9, k = idx & 511;
        o[j] = f2bf(W1[(size_t)k * 256 + n]);
      }
      *(u16x8*)&W1T[idx8] = o;
    } else if (idx8 < 196608) {                // W2 [256x256] -> W2T [256x256]
      int j0 = idx8 - 131072;
#pragma unroll
      for (int j = 0; j < 8; j++) {
        int idx = j0 + j; int n = idx >> 8, k = idx & 255;
        o[j] = f2bf(W2[(size_t)k * 256 + n]);
      }
      *(u16x8*)&W2T[j0] = o;
    } else if (idx8 < 212992) {                // W3 [256x64] -> W3T [64x256]
      int j0 = idx8 - 196608;
#pragma unroll
      for (int j = 0; j < 8; j++) {
        int idx = j0 + j; int n = idx >> 8, k = idx & 255;
        o[j] = f2bf(W3[(size_t)k * 64 + n]);
      }
      *(u16x8*)&W3T[j0] = o;
    }
  } else {
    // degree count (cnt pre-zeroed by gcn_zero_k in a prior launch)
    int e = (b - XB_BLOCKS - WB_BLOCKS) * 256 + threadIdx.x;
    if (e < E) atomicAdd(&cnt[dst[e]], 1);
  }
}

// ---------- scan ----------
__global__ __launch_bounds__(256) void gcn_scan_blocks_k(
    const int* __restrict__ cnt, int* __restrict__ blockSum, int nNodes) {
  __shared__ int sw[4];
  int t = threadIdx.x;
  int i = blockIdx.x * 256 + t;
  int v = (i < nNodes) ? cnt[i] : 0;
  for (int off = 32; off > 0; off >>= 1) v += __shfl_down(v, off);
  if ((t & 63) == 0) sw[t >> 6] = v;
  __syncthreads();
  if (t == 0) blockSum[blockIdx.x] = sw[0] + sw[1] + sw[2] + sw[3];
}

__global__ __launch_bounds__(256) void gcn_scan_tops_k(
    int* __restrict__ blockSum, int nBlocks) {
  __shared__ int sb[256];
  int t = threadIdx.x;
  int v = (t < nBlocks) ? blockSum[t] : 0;
  sb[t] = v;
  __syncthreads();
  for (int off = 1; off < 256; off <<= 1) {
    int x = (t >= off) ? sb[t - off] : 0;
    __syncthreads();
    sb[t] += x;
    __syncthreads();
  }
  if (t < nBlocks) blockSum[t] = sb[t] - v;  // exclusive
}

__global__ __launch_bounds__(256) void gcn_scan_final_k(
    const int* __restrict__ cnt, const int* __restrict__ blockSum,
    int* __restrict__ rs, int* __restrict__ cur, float* __restrict__ dinv,
    int nNodes, int E) {
  __shared__ int sb[256];
  int t = threadIdx.x;
  int i = blockIdx.x * 256 + t;
  int v = (i < nNodes) ? cnt[i] : 0;
  sb[t] = v;
  __syncthreads();
  for (int off = 1; off < 256; off <<= 1) {
    int x = (t >= off) ? sb[t - off] : 0;
    __syncthreads();
    sb[t] += x;
    __syncthreads();
  }
  if (i < nNodes) {
    int off = blockSum[blockIdx.x] + sb[t] - v;
    rs[i] = off; cur[i] = off;
    dinv[i] = rsqrtf(1.0f + (float)v);
  }
  if (i == 0) rs[nNodes] = E;
}

// scatter edges sorted by dst; pack (src, norm) into one int2
__global__ void gcn_scatter_k(const int* __restrict__ src, const int* __restrict__ dst,
                              int* __restrict__ cur, const float* __restrict__ dinv,
                              int2* __restrict__ e2, int E) {
  int e = blockIdx.x * 256 + threadIdx.x;
  if (e < E) {
    int d = dst[e];
    int s = src[e];
    int p = atomicAdd(&cur[d], 1);
    int2 v; v.x = s; v.y = __float_as_int(dinv[s] * dinv[d]);
    e2[p] = v;
  }
}

// ---------- bf16 MFMA GEMM, fp8 e4m3 output: C8 = fp8(A @ Bt^T) ----------
template<int BN, int WTN>
__global__ __launch_bounds__(256) void gcn_gemm_k(
    const unsigned short* __restrict__ A,   // [MPAD x K] bf16
    const unsigned short* __restrict__ Bt,  // [N x K]    bf16
    unsigned char* __restrict__ C8,         // [MPAD x N] fp8
    int K, int N) {
  __shared__ __align__(16) unsigned short lds_a[128 * 32];
  __shared__ __align__(16) unsigned short lds_b[BN * 32];
  const int t = threadIdx.x;
  const int wave = t >> 6, lane = t & 63;
  const int wr = wave >> 1, wc = wave & 1;
  const int quad = lane >> 4, lrow = lane & 15;
  const int m0 = blockIdx.x * 128;
  const int n0 = blockIdx.y * BN;

  f32x4 acc[4][WTN] = {};

  for (int k0 = 0; k0 < K; k0 += 32) {
    __syncthreads();
    for (int q = t; q < 512; q += 256) {
      int r = q >> 2, c = (q & 3) * 8;
      async_copy16(&A[(size_t)(m0 + r) * K + k0 + c], &lds_a[q * 8]);
    }
    for (int q = t; q < BN * 4; q += 256) {
      int r = q >> 2, c = (q & 3) * 8;
      async_copy16(&Bt[(size_t)(n0 + r) * K + k0 + c], &lds_b[q * 8]);
    }
    __syncthreads();
    bf16x8 af[4], bfr[WTN];
#pragma unroll
    for (int mt = 0; mt < 4; mt++)
      af[mt] = *(const bf16x8*)&lds_a[(wr * 64 + mt * 16 + lrow) * 32 + quad * 8];
#pragma unroll
    for (int nt = 0; nt < WTN; nt++)
      bfr[nt] = *(const bf16x8*)&lds_b[(wc * (BN / 2) + nt * 16 + lrow) * 32 + quad * 8];
#pragma unroll
    for (int mt = 0; mt < 4; mt++)
#pragma unroll
      for (int nt = 0; nt < WTN; nt++)
        acc[mt][nt] = __builtin_amdgcn_mfma_f32_16x16x32_bf16(af[mt], bfr[nt], acc[mt][nt], 0, 0, 0);
  }

#pragma unroll
  for (int mt = 0; mt < 4; mt++)
#pragma unroll
    for (int nt = 0; nt < WTN; nt++)
#pragma unroll
      for (int r = 0; r < 4; r++) {
        int row = m0 + wr * 64 + mt * 16 + quad * 4 + r;
        int col = n0 + wc * (BN / 2) + nt * 16 + lrow;
        C8[(size_t)row * N + col] = f2fp8(acc[mt][nt][r]);
      }
}

// ---------- aggregation over fp8 rows, fused bias+self+ReLU, bf16 out ----------
// 2 edges per wave (32 lanes x 8B fp8 per row), unroll x4 -> 8 edges in flight.
template<int D>  // D = 256
__global__ __launch_bounds__(256) void gcn_agg_relu_k(
    const unsigned char* __restrict__ h8, const int* __restrict__ rs,
    const int2* __restrict__ e2, const float* __restrict__ dinv,
    const float* __restrict__ bias, unsigned short* __restrict__ out, int nNodes) {
  int wave = threadIdx.x >> 6, lane = threadIdx.x & 63;
  int i = blockIdx.x * 4 + wave;
  if (i >= nNodes) return;
  int half = lane >> 5, sub = lane & 31;
  int f0 = sub * 8;
  float di = dinv[i];
  uint2 dsel = *(const uint2*)&h8[(size_t)i * D + f0];
  float sv[8];
  fp8x8_to_f32(dsel, sv);
  float wself = (half == 0) ? di * di : 0.0f;
  float acc[8];
#pragma unroll
  for (int j = 0; j < 8; j++) acc[j] = sv[j] * wself;

  int e0 = rs[i], e1 = rs[i + 1];
  int nIter = (e1 - e0 + 7) >> 3;
  int e = e0 + half;
  for (int k = 0; k < nIter; k++) {
    int idx[4]; float w[4];
#pragma unroll
    for (int u = 0; u < 4; u++) {
      int ee = e + 2 * u;
      bool v = ee < e1;
      int2 pr = e2[v ? ee : e0];
      idx[u] = v ? pr.x : i;
      w[u] = v ? __int_as_float(pr.y) : 0.0f;
    }
    uint2 d0 = *(const uint2*)&h8[(size_t)idx[0] * D + f0];
    uint2 d1 = *(const uint2*)&h8[(size_t)idx[1] * D + f0];
    uint2 d2 = *(const uint2*)&h8[(size_t)idx[2] * D + f0];
    uint2 d3 = *(const uint2*)&h8[(size_t)idx[3] * D + f0];
    float r0[8], r1[8], r2[8], r3[8];
    fp8x8_to_f32(d0, r0); fp8x8_to_f32(d1, r1);
    fp8x8_to_f32(d2, r2); fp8x8_to_f32(d3, r3);
#pragma unroll
    for (int j = 0; j < 8; j++)
      acc[j] += r0[j] * w[0] + r1[j] * w[1] + r2[j] * w[2] + r3[j] * w[3];
    e += 8;
  }
#pragma unroll
  for (int j = 0; j < 8; j++) acc[j] += __shfl_xor(acc[j], 32);
  if (half == 0) {
    u16x8 o;
#pragma unroll
    for (int j = 0; j < 8; j++) {
      float r = acc[j] + bias[f0 + j];
      o[j] = f2bf(r > 0.0f ? r : 0.0f);
    }
    *(u16x8*)&out[(size_t)i * D + f0] = o;
  }
}

// final layer: D=64 fp8 rows; 4 edges per wave (16 lanes x 4B), softmax+log_softmax
__global__ __launch_bounds__(256) void gcn_agg_final_k(
    const unsigned char* __restrict__ h8, const int* __restrict__ rs,
    const int2* __restrict__ e2, const float* __restrict__ dinv,
    const float* __restrict__ bias, float* __restrict__ out, int nNodes) {
  int wave = threadIdx.x >> 6, lane = threadIdx.x & 63;
  int i = blockIdx.x * 4 + wave;
  if (i >= nNodes) return;
  int qtr = lane >> 4, sub = lane & 15;
  int f0 = sub * 4;
  float di = dinv[i];
  unsigned int dself = *(const unsigned int*)&h8[(size_t)i * 64 + f0];
  float sv[4];
  fp8x4_to_f32(dself, sv);
  float wself = (qtr == 0) ? di * di : 0.0f;
  float acc[4];
#pragma unroll
  for (int j = 0; j < 4; j++) acc[j] = sv[j] * wself;

  int e0 = rs[i], e1 = rs[i + 1];
  int nIter = (e1 - e0 + 7) >> 3;
  int e = e0 + qtr;
  for (int k = 0; k < nIter; k++) {
    int idx[2]; float w[2];
#pragma unroll
    for (int u = 0; u < 2; u++) {
      int ee = e + 4 * u;
      bool v = ee < e1;
      int2 pr = e2[v ? ee : e0];
      idx[u] = v ? pr.x : i;
      w[u] = v ? __int_as_float(pr.y) : 0.0f;
    }
    unsigned int d0 = *(const unsigned int*)&h8[(size_t)idx[0] * 64 + f0];
    unsigned int d1 = *(const unsigned int*)&h8[(size_t)idx[1] * 64 + f0];
    float r0[4], r1[4];
    fp8x4_to_f32(d0, r0); fp8x4_to_f32(d1, r1);
#pragma unroll
    for (int j = 0; j < 4; j++)
      acc[j] += r0[j] * w[0] + r1[j] * w[1];
    e += 8;
  }
#pragma unroll
  for (int j = 0; j < 4; j++) {
    acc[j] += __shfl_xor(acc[j], 16);
    acc[j] += __shfl_xor(acc[j], 32);
    acc[j] += bias[f0 + j];
  }
  // softmax over 64 features (16 lanes x 4 regs; all lanes hold full sums)
  float m = fmaxf(fmaxf(acc[0], acc[1]), fmaxf(acc[2], acc[3]));
#pragma unroll
  for (int off = 8; off > 0; off >>= 1) m = fmaxf(m, __shfl_xor(m, off));
  float ex[4], s = 0.0f;
#pragma unroll
  for (int j = 0; j < 4; j++) { ex[j] = __expf(acc[j] - m); s += ex[j]; }
#pragma unroll
  for (int off = 8; off > 0; off >>= 1) s += __shfl_xor(s, off);
  float rcs = 1.0f / s;
  float p[4], s2 = 0.0f;
#pragma unroll
  for (int j = 0; j < 4; j++) { p[j] = ex[j] * rcs; s2 += __expf(p[j]); }
#pragma unroll
  for (int off = 8; off > 0; off >>= 1) s2 += __shfl_xor(s2, off);
  float ls = __logf(s2);
  if (qtr == 0) {
    float4 o; o.x = p[0] - ls; o.y = p[1] - ls; o.z = p[2] - ls; o.w = p[3] - ls;
    *(float4*)&out[(size_t)i * 64 + f0] = o;
  }
}

// ---------- launch ----------
extern "C" void kernel_launch(void* const* d_in, const int* in_sizes, int n_in,
                              void* d_out, int out_size, void* d_ws, size_t ws_size,
                              hipStream_t stream) {
  const float* x    = (const float*)d_in[0];
  const int*   eidx = (const int*)d_in[1];
  const float* W1   = (const float*)d_in[2];
  const float* b1   = (const float*)d_in[3];
  const float* W2   = (const float*)d_in[4];
  const float* b2   = (const float*)d_in[5];
  const float* W3   = (const float*)d_in[6];
  const float* b3   = (const float*)d_in[7];
  float* out = (float*)d_out;

  const int E = in_sizes[1] / 2;            // 800000
  const int* src = eidx;
  const int* dst = eidx + E;

  char* p = (char*)d_ws;
  auto alloc = [&](size_t bytes) -> void* {
    void* r = (void*)p;
    p += (bytes + 255) & ~(size_t)255;
    return r;
  };
  unsigned short* xb  = (unsigned short*)alloc((size_t)MPAD * 512 * 2);
  unsigned char*  h8  = (unsigned char*)alloc((size_t)MPAD * 256);   // fp8 gemm out
  unsigned short* ab  = (unsigned short*)alloc((size_t)MPAD * 256 * 2);  // agg out (bf16)
  unsigned char*  h83 = (unsigned char*)alloc((size_t)MPAD * 64);
  unsigned short* W1T = (unsigned short*)alloc((size_t)256 * 512 * 2);
  unsigned short* W2T = (unsigned short*)alloc((size_t)256 * 256 * 2);
  unsigned short* W3T = (unsigned short*)alloc((size_t)64 * 256 * 2);
  int*   cnt  = (int*)alloc((size_t)NN * 4);
  int*   rs   = (int*)alloc((size_t)(NN + 1) * 4);
  int*   cur  = (int*)alloc((size_t)NN * 4);
  float* dinv = (float*)alloc((size_t)NN * 4);
  int2*  e2   = (int2*)alloc((size_t)E * 8);
  int*   bsum = (int*)alloc((size_t)SCAN_BLOCKS * 4);

  const int EB = (E + 255) / 256;
  gcn_zero_k<<<SCAN_BLOCKS, 256, 0, stream>>>(cnt, NN);
  gcn_prep_k<<<XB_BLOCKS + WB_BLOCKS + EB, 256, 0, stream>>>(
      x, xb, W1, W2, W3, W1T, W2T, W3T, dst, cnt, E);
  gcn_scan_blocks_k<<<SCAN_BLOCKS, 256, 0, stream>>>(cnt, bsum, NN);
  gcn_scan_tops_k<<<1, 256, 0, stream>>>(bsum, SCAN_BLOCKS);
  gcn_scan_final_k<<<SCAN_BLOCKS, 256, 0, stream>>>(cnt, bsum, rs, cur, dinv, NN, E);
  gcn_scatter_k<<<EB, 256, 0, stream>>>(src, dst, cur, dinv, e2, E);

  const int MB = MPAD / 128;  // 391
  // layer 1
  gcn_gemm_k<128, 4><<<dim3(MB, 2), 256, 0, stream>>>(xb, W1T, h8, 512, 256);
  gcn_agg_relu_k<256><<<(NN + 3) / 4, 256, 0, stream>>>(h8, rs, e2, dinv, b1, ab, NN);
  // layer 2
  gcn_gemm_k<128, 4><<<dim3(MB, 2), 256, 0, stream>>>(ab, W2T, h8, 256, 256);
  gcn_agg_relu_k<256><<<(NN + 3) / 4, 256, 0, stream>>>(h8, rs, e2, dinv, b2, ab, NN);
  // layer 3 + fused softmax/log_softmax
  gcn_gemm_k<64, 2><<<dim3(MB, 1), 256, 0, stream>>>(ab, W3T, h83, 256, 64);
  gcn_agg_final_k<<<(NN + 3) / 4, 256, 0, stream>>>(h83, rs, e2, dinv, b3, out, NN);

  (void)n_in; (void)out_size; (void)ws_size;
}